// Round 9
// baseline (58.026 us; speedup 1.0000x reference)
//
#include <hip/hip_runtime.h>

typedef float v2f __attribute__((ext_vector_type(2)));

constexpr int BN   = 131072;   // points
constexpr int HID  = 20;       // hidden width
constexpr int NLAY = 7;        // hidden->hidden layers

// LDS layout (floats)
constexpr int OFF_WH   = 0;      // 7*20*20 = 2800
constexpr int OFF_BH   = 2800;   // 7*20    = 140
constexpr int OFF_WIN  = 2940;   // 3*20    = 60
constexpr int OFF_BIN  = 3000;   // 20
constexpr int OFF_WOUT = 3020;   // 20*2    = 40
constexpr int OFF_BOUT = 3060;   // 2
constexpr int LDS_TOT  = 3064;

// ws slots (slow path only)
enum { S_PX = 0, S_PXX, S_PXXX, S_P, S_GPX,
       S_PY, S_PYY, S_PYYY, S_GPY,
       S_D2P, S_D3P, S_D3M, S_XT, S_YT, NSLOT };

__device__ __forceinline__ float fast_tanh(float a) {
    float e = __builtin_amdgcn_exp2f(a * 2.8853900817779268f);
    float r = __builtin_amdgcn_rcpf(e + 1.0f);
    return __builtin_fmaf(-2.0f, r, 1.0f);
}
__device__ __forceinline__ v2f tanh2(v2f a) {
    v2f r; r.x = fast_tanh(a.x); r.y = fast_tanh(a.y); return r;
}
__device__ __forceinline__ v2f splat(float s) { v2f r = {s, s}; return r; }
#define FMA2(a, b, c) __builtin_elementwise_fma((a), (b), (c))

// acc += bcast(src0.lo) * src1   (per-half: acc.h += src0.lo * src1.h)
__device__ __forceinline__ void pk_fma_blo(v2f& acc, const v2f b, const v2f s) {
    asm("v_pk_fma_f32 %0, %1, %2, %0 op_sel:[0,0,0] op_sel_hi:[0,1,1]"
        : "+v"(acc) : "v"(b), "v"(s));
}
// acc += bcast(src0.hi) * src1
__device__ __forceinline__ void pk_fma_bhi(v2f& acc, const v2f b, const v2f s) {
    asm("v_pk_fma_f32 %0, %1, %2, %0 op_sel:[1,0,0] op_sel_hi:[1,1,1]"
        : "+v"(acc) : "v"(b), "v"(s));
}

__device__ __forceinline__ void stage_weights(
    float* smem, const float* Win, const float* bin, const float* Wh,
    const float* bh, const float* Wout, const float* bout)
{
    const int tid = threadIdx.x;
    for (int i = tid; i < 2800; i += 256) smem[OFF_WH + i] = Wh[i];
    for (int i = tid; i < 140;  i += 256) smem[OFF_BH + i] = bh[i];
    if (tid < 60) smem[OFF_WIN  + tid] = Win[tid];
    if (tid < 20) smem[OFF_BIN  + tid] = bin[tid];
    if (tid < 40) smem[OFF_WOUT + tid] = Wout[tid];
    if (tid < 2)  smem[OFF_BOUT + tid] = bout[tid];
    __syncthreads();
}

// ---------------------------------------------------------------- FAST PATH
// lambda1 == lambda2 == 0.  TWO POINTS PER THREAD, packed in v2f halves.
// State: V/DX/DY[neuron] = {val(pt0), val(pt1)}.  Weight scalars broadcast
// via v_pk_fma op_sel -> zero shuffles, half the LDS reads per point.
__global__ __launch_bounds__(256, 1) void pinn_fast3(
    const float* __restrict__ x, const float* __restrict__ y, const float* __restrict__ t,
    const float* __restrict__ u, const float* __restrict__ v,
    const float* __restrict__ Win, const float* __restrict__ bin,
    const float* __restrict__ Wh,  const float* __restrict__ bh,
    const float* __restrict__ Wout,const float* __restrict__ bout,
    const float* __restrict__ lam1p, const float* __restrict__ lam2p,
    float* __restrict__ out)
{
    if (lam1p[0] != 0.0f || lam2p[0] != 0.0f) return;   // slow path covers

    __shared__ __align__(16) float smem[LDS_TOT];
    __shared__ float wsum[4];
    stage_weights(smem, Win, bin, Wh, bh, Wout, bout);

    const int tid = threadIdx.x;
    const int g   = blockIdx.x * 256 + tid;   // pair index: points 2g, 2g+1

    const v2f xv2 = *(const v2f*)&x[2 * g];
    const v2f yv2 = *(const v2f*)&y[2 * g];
    const v2f tv2 = *(const v2f*)&t[2 * g];

    v2f V[20], DX[20], DY[20];

    // ---- input layer
    #pragma unroll
    for (int n = 0; n < 20; ++n) {
        const v2f w0 = splat(smem[OFF_WIN + n]);
        const v2f w1 = splat(smem[OFF_WIN + HID + n]);
        const v2f w2 = splat(smem[OFF_WIN + 2 * HID + n]);
        v2f av = splat(smem[OFF_BIN + n]);
        av = FMA2(xv2, w0, av);
        av = FMA2(yv2, w1, av);
        av = FMA2(tv2, w2, av);
        v2f s  = tanh2(av);
        v2f s1 = 1.0f - s * s;
        V[n]  = s;
        DX[n] = s1 * w0;
        DY[n] = s1 * w1;
    }

    // ---- hidden layers
    #pragma unroll 1
    for (int l = 0; l < NLAY; ++l) {
        const float* Wl = &smem[OFF_WH + l * (HID * HID)];
        const float* bl = &smem[OFF_BH + l * HID];

        v2f aV[20], aX[20], aY[20];
        #pragma unroll
        for (int o = 0; o < 20; ++o) { aV[o] = splat(0.f); aX[o] = splat(0.f); aY[o] = splat(0.f); }

        #pragma unroll
        for (int i = 0; i < 20; ++i) {        // input neuron
            #pragma unroll
            for (int b = 0; b < 5; ++b) {     // output quad (4b .. 4b+3)
                float4 w = *(const float4*)&Wl[i * HID + 4 * b];
                v2f wab = {w.x, w.y}, wcd = {w.z, w.w};
                pk_fma_blo(aV[4*b+0], wab, V[i]);
                pk_fma_bhi(aV[4*b+1], wab, V[i]);
                pk_fma_blo(aV[4*b+2], wcd, V[i]);
                pk_fma_bhi(aV[4*b+3], wcd, V[i]);
                pk_fma_blo(aX[4*b+0], wab, DX[i]);
                pk_fma_bhi(aX[4*b+1], wab, DX[i]);
                pk_fma_blo(aX[4*b+2], wcd, DX[i]);
                pk_fma_bhi(aX[4*b+3], wcd, DX[i]);
                pk_fma_blo(aY[4*b+0], wab, DY[i]);
                pk_fma_bhi(aY[4*b+1], wab, DY[i]);
                pk_fma_blo(aY[4*b+2], wcd, DY[i]);
                pk_fma_bhi(aY[4*b+3], wcd, DY[i]);
            }
        }

        #pragma unroll
        for (int n = 0; n < 20; ++n) {
            v2f a0 = aV[n] + splat(bl[n]);
            v2f s  = tanh2(a0);
            v2f s1 = 1.0f - s * s;
            V[n]  = s;
            DX[n] = s1 * aX[n];
            DY[n] = s1 * aY[n];
        }
    }

    // ---- output layer: col0 -> psi, col1 -> p (per-point, packed in halves)
    v2f dX = splat(0.f), dY = splat(0.f), dP = splat(0.f),
        dPX = splat(0.f), dPY = splat(0.f);
    #pragma unroll
    for (int n = 0; n < 20; ++n) {
        const v2f w0n = splat(smem[OFF_WOUT + 2 * n]);
        const v2f w1n = splat(smem[OFF_WOUT + 2 * n + 1]);
        dX  = FMA2(DX[n], w0n, dX);
        dY  = FMA2(DY[n], w0n, dY);
        dP  = FMA2(V[n],  w1n, dP);
        dPX = FMA2(DX[n], w1n, dPX);
        dPY = FMA2(DY[n], w1n, dPY);
    }
    const v2f pvv = dP + splat(smem[OFF_BOUT + 1]);

    // preds: out[3p] = p, out[3p+1] = psi_y, out[3p+2] = -psi_x
    const int p0 = 2 * g;
    out[3*p0+0] = pvv.x;
    out[3*p0+1] = dY.x;
    out[3*p0+2] = -dX.x;
    out[3*p0+3] = pvv.y;
    out[3*p0+4] = dY.y;
    out[3*p0+5] = -dX.y;

    const v2f uv2 = *(const v2f*)&u[2 * g];
    const v2f vv2 = *(const v2f*)&v[2 * g];
    const v2f du = uv2 - dY;
    const v2f dv = vv2 + dX;     // v - (-psi_x)
    // lambda1 = lambda2 = 0 => f_u = p_x, f_v = p_y
    const v2f tv = du * du + dv * dv + dPX * dPX + dPY * dPY;
    float term = tv.x + tv.y;

    #pragma unroll
    for (int off = 32; off > 0; off >>= 1) term += __shfl_down(term, off);
    const int lane = tid & 63, wid = tid >> 6;
    if (lane == 0) wsum[wid] = term;
    __syncthreads();
    if (tid == 0) atomicAdd(&out[3*BN], wsum[0] + wsum[1] + wsum[2] + wsum[3]);
}

// ---------------------------------------------------------------- SLOW PATH (lambda != 0)
__device__ __forceinline__ void pk_fma_lo(v2f& acc, const v2f s, const v2f w) {
    asm("v_pk_fma_f32 %0, %1, %2, %0 op_sel:[0,0,0] op_sel_hi:[0,1,1]"
        : "+v"(acc) : "v"(s), "v"(w));
}
__device__ __forceinline__ void pk_fma_hi(v2f& acc, const v2f s, const v2f w) {
    asm("v_pk_fma_f32 %0, %1, %2, %0 op_sel:[1,0,0] op_sel_hi:[1,1,1]"
        : "+v"(acc) : "v"(s), "v"(w));
}

template<bool BIASED>
__device__ __forceinline__ void sweep2(const v2f (&S1)[10], const v2f (&S2)[10],
                                       v2f (&A1)[10], v2f (&A2)[10],
                                       const float* __restrict__ Wl,
                                       const float* __restrict__ bl)
{
    #pragma unroll
    for (int j = 0; j < 10; ++j) {
        if (BIASED) { A1[j].x = bl[2*j]; A1[j].y = bl[2*j+1]; }
        else        A1[j] = splat(0.f);
        A2[j] = splat(0.f);
    }
    #pragma unroll
    for (int i = 0; i < 10; ++i) {
        const float* r0 = &Wl[(2 * i) * HID];
        const float* r1 = &Wl[(2 * i + 1) * HID];
        #pragma unroll
        for (int ob = 0; ob < 5; ++ob) {
            float4 w0 = *(const float4*)&r0[4 * ob];
            float4 w1 = *(const float4*)&r1[4 * ob];
            v2f w0a = {w0.x, w0.y}, w0b = {w0.z, w0.w};
            v2f w1a = {w1.x, w1.y}, w1b = {w1.z, w1.w};
            pk_fma_lo(A1[2*ob],   S1[i], w0a);
            pk_fma_lo(A1[2*ob+1], S1[i], w0b);
            pk_fma_hi(A1[2*ob],   S1[i], w1a);
            pk_fma_hi(A1[2*ob+1], S1[i], w1b);
            pk_fma_lo(A2[2*ob],   S2[i], w0a);
            pk_fma_lo(A2[2*ob+1], S2[i], w0b);
            pk_fma_hi(A2[2*ob],   S2[i], w1a);
            pk_fma_hi(A2[2*ob+1], S2[i], w1b);
        }
    }
}

__global__ __launch_bounds__(256, 3) void pinn_jets6(
    const float* __restrict__ x, const float* __restrict__ y, const float* __restrict__ t,
    const float* __restrict__ Win, const float* __restrict__ bin,
    const float* __restrict__ Wh,  const float* __restrict__ bh,
    const float* __restrict__ Wout,const float* __restrict__ bout,
    const float* __restrict__ lam1p, const float* __restrict__ lam2p,
    float* __restrict__ ws)
{
    if (lam1p[0] == 0.0f && lam2p[0] == 0.0f) return;   // fast path covers

    __shared__ __align__(16) float smem[LDS_TOT];
    stage_weights(smem, Win, bin, Wh, bh, Wout, bout);

    const int pt    = blockIdx.x * 256 + threadIdx.x;
    const int slice = blockIdx.y;

    const float xv = x[pt], yv = y[pt], tv = t[pt];
    const v2f xv2 = splat(xv), yv2 = splat(yv), tv2 = splat(tv);

    if (slice < 4) {
        const float DXT[4] = {1.f, 0.f, 1.f,  1.f};
        const float DYT[4] = {0.f, 1.f, 1.f, -1.f};
        const v2f dxv = splat(DXT[slice]), dyv = splat(DYT[slice]);

        v2f V[10], D1[10], D2[10], D3[10];

        #pragma unroll
        for (int j = 0; j < 10; ++j) {
            v2f w0 = *(const v2f*)&smem[OFF_WIN + 2*j];
            v2f w1 = *(const v2f*)&smem[OFF_WIN + HID + 2*j];
            v2f w2 = *(const v2f*)&smem[OFF_WIN + 2*HID + 2*j];
            v2f av = *(const v2f*)&smem[OFF_BIN + 2*j];
            av = FMA2(xv2, w0, av);
            av = FMA2(yv2, w1, av);
            av = FMA2(tv2, w2, av);
            v2f a1 = dxv * w0;
            a1 = FMA2(dyv, w1, a1);
            v2f s  = tanh2(av);
            v2f s2 = s * s;
            v2f s1 = 1.0f - s2;
            v2f f2 = -2.0f * s * s1;
            v2f f3 = s1 * (4.0f * s2 - 2.0f * s1);
            v2f a1sq = a1 * a1;
            V[j]  = s;
            D1[j] = s1 * a1;
            D2[j] = f2 * a1sq;
            D3[j] = f3 * a1sq * a1;
        }

        #pragma unroll 1
        for (int l = 0; l < NLAY; ++l) {
            const float* Wl = &smem[OFF_WH + l * (HID * HID)];
            const float* bl = &smem[OFF_BH + l * HID];
            v2f aV[10], a1[10];
            sweep2<true >(V,  D1, aV, a1, Wl, bl);
            v2f a2[10], a3[10];
            sweep2<false>(D2, D3, a2, a3, Wl, bl);
            #pragma unroll
            for (int j = 0; j < 10; ++j) {
                v2f s  = tanh2(aV[j]);
                v2f s2 = s * s;
                v2f s1 = 1.0f - s2;
                v2f f2 = -2.0f * s * s1;
                v2f f3 = s1 * (4.0f * s2 - 2.0f * s1);
                v2f u1 = a1[j];
                v2f u1sq = u1 * u1;
                V[j]  = s;
                D1[j] = s1 * u1;
                D2[j] = s1 * a2[j] + f2 * u1sq;
                D3[j] = s1 * a3[j] + 3.0f * f2 * (u1 * a2[j]) + f3 * u1sq * u1;
            }
        }

        v2f d1 = splat(0.f), d2 = splat(0.f), d3 = splat(0.f),
            dP = splat(0.f), dP1 = splat(0.f);
        #pragma unroll
        for (int j = 0; j < 10; ++j) {
            v2f w0j = {smem[OFF_WOUT + 4*j],     smem[OFF_WOUT + 4*j + 2]};
            v2f w1j = {smem[OFF_WOUT + 4*j + 1], smem[OFF_WOUT + 4*j + 3]};
            d1  = FMA2(D1[j], w0j, d1);
            d2  = FMA2(D2[j], w0j, d2);
            d3  = FMA2(D3[j], w0j, d3);
            dP  = FMA2(V[j],  w1j, dP);
            dP1 = FMA2(D1[j], w1j, dP1);
        }
        const float r1 = d1.x + d1.y;
        const float r2 = d2.x + d2.y;
        const float r3 = d3.x + d3.y;

        switch (slice) {
            case 0:
                ws[S_PX  *BN+pt] = r1;
                ws[S_PXX *BN+pt] = r2;
                ws[S_PXXX*BN+pt] = r3;
                ws[S_P   *BN+pt] = smem[OFF_BOUT + 1] + dP.x + dP.y;
                ws[S_GPX *BN+pt] = dP1.x + dP1.y;
                break;
            case 1:
                ws[S_PY  *BN+pt] = r1;
                ws[S_PYY *BN+pt] = r2;
                ws[S_PYYY*BN+pt] = r3;
                ws[S_GPY *BN+pt] = dP1.x + dP1.y;
                break;
            case 2:
                ws[S_D2P *BN+pt] = r2;
                ws[S_D3P *BN+pt] = r3;
                break;
            default:
                ws[S_D3M *BN+pt] = r3;
                break;
        }
    } else {
        v2f V[10], DA[10], DT[10], DAT[10];

        #pragma unroll
        for (int j = 0; j < 10; ++j) {
            v2f w0 = *(const v2f*)&smem[OFF_WIN + 2*j];
            v2f w1 = *(const v2f*)&smem[OFF_WIN + HID + 2*j];
            v2f w2 = *(const v2f*)&smem[OFF_WIN + 2*HID + 2*j];
            v2f av = *(const v2f*)&smem[OFF_BIN + 2*j];
            av = FMA2(xv2, w0, av);
            av = FMA2(yv2, w1, av);
            av = FMA2(tv2, w2, av);
            v2f wa = (slice == 4) ? w0 : w1;
            v2f s  = tanh2(av);
            v2f s1 = 1.0f - s * s;
            v2f f2 = -2.0f * s * s1;
            V[j]   = s;
            DA[j]  = s1 * wa;
            DT[j]  = s1 * w2;
            DAT[j] = f2 * wa * w2;
        }

        #pragma unroll 1
        for (int l = 0; l < NLAY; ++l) {
            const float* Wl = &smem[OFF_WH + l * (HID * HID)];
            const float* bl = &smem[OFF_BH + l * HID];
            v2f aV[10], aA[10];
            sweep2<true >(V,  DA,  aV, aA, Wl, bl);
            v2f aT[10], aAT[10];
            sweep2<false>(DT, DAT, aT, aAT, Wl, bl);
            #pragma unroll
            for (int j = 0; j < 10; ++j) {
                v2f s  = tanh2(aV[j]);
                v2f s1 = 1.0f - s * s;
                v2f f2 = -2.0f * s * s1;
                V[j]   = s;
                DA[j]  = s1 * aA[j];
                DT[j]  = s1 * aT[j];
                DAT[j] = f2 * (aA[j] * aT[j]) + s1 * aAT[j];
            }
        }

        v2f dAT = splat(0.f);
        #pragma unroll
        for (int j = 0; j < 10; ++j) {
            v2f w0j = {smem[OFF_WOUT + 4*j], smem[OFF_WOUT + 4*j + 2]};
            dAT = FMA2(DAT[j], w0j, dAT);
        }
        const float r = dAT.x + dAT.y;
        if (slice == 4) ws[S_XT*BN+pt] = r;
        else            ws[S_YT*BN+pt] = r;
    }
}

__global__ __launch_bounds__(256) void pinn_combine(
    const float* __restrict__ ws,
    const float* __restrict__ u, const float* __restrict__ v,
    const float* __restrict__ lam1p, const float* __restrict__ lam2p,
    float* __restrict__ out)
{
    if (lam1p[0] == 0.0f && lam2p[0] == 0.0f) return;   // fast path covers

    __shared__ float wsum[4];
    const int tid = threadIdx.x;
    const int pt  = blockIdx.x * 256 + tid;

    const float psi_x   = ws[S_PX  *BN+pt];
    const float psi_xx  = ws[S_PXX *BN+pt];
    const float psi_xxx = ws[S_PXXX*BN+pt];
    const float pv      = ws[S_P   *BN+pt];
    const float p_x     = ws[S_GPX *BN+pt];
    const float psi_y   = ws[S_PY  *BN+pt];
    const float psi_yy  = ws[S_PYY *BN+pt];
    const float psi_yyy = ws[S_PYYY*BN+pt];
    const float p_y     = ws[S_GPY *BN+pt];
    const float d2p     = ws[S_D2P *BN+pt];
    const float d3p     = ws[S_D3P *BN+pt];
    const float d3m     = ws[S_D3M *BN+pt];
    const float psi_xt  = ws[S_XT  *BN+pt];
    const float psi_yt  = ws[S_YT  *BN+pt];

    const float psi_xy  = 0.5f * (d2p - psi_xx - psi_yy);
    const float psi_xxy = (d3p - d3m - 2.0f * psi_yyy) * (1.0f / 6.0f);
    const float psi_xyy = (d3p + d3m - 2.0f * psi_xxx) * (1.0f / 6.0f);

    const float u_pred = psi_y;
    const float v_pred = -psi_x;
    const float u_x = psi_xy,  u_y = psi_yy,  u_t = psi_yt;
    const float v_x = -psi_xx, v_y = -psi_xy, v_t = -psi_xt;
    const float u_xx = psi_xxy, u_yy = psi_yyy;
    const float v_xx = -psi_xxx, v_yy = -psi_xyy;

    const float lam1 = lam1p[0];
    const float lam2 = lam2p[0];

    const float f_u = lam1 * (u_t + u_pred * u_x + v_pred * u_y) + p_x - lam2 * (u_xx + u_yy);
    const float f_v = lam1 * (v_t + u_pred * v_x + v_pred * v_y) - lam1 * 9.81f + p_y
                      - lam2 * (v_xx + v_yy);

    out[3*pt+0] = pv;
    out[3*pt+1] = u_pred;
    out[3*pt+2] = v_pred;

    const float du = u[pt] - u_pred;
    const float dv = v[pt] - v_pred;
    float term = du * du + dv * dv + f_u * f_u + f_v * f_v;

    #pragma unroll
    for (int off = 32; off > 0; off >>= 1) term += __shfl_down(term, off);
    const int lane = tid & 63, wid = tid >> 6;
    if (lane == 0) wsum[wid] = term;
    __syncthreads();
    if (tid == 0) atomicAdd(&out[3*BN], wsum[0] + wsum[1] + wsum[2] + wsum[3]);
}

extern "C" void kernel_launch(void* const* d_in, const int* in_sizes, int n_in,
                              void* d_out, int out_size, void* d_ws, size_t ws_size,
                              hipStream_t stream) {
    const float* x    = (const float*)d_in[0];
    const float* y    = (const float*)d_in[1];
    const float* t    = (const float*)d_in[2];
    const float* u    = (const float*)d_in[3];
    const float* v    = (const float*)d_in[4];
    const float* Win  = (const float*)d_in[5];
    const float* bin  = (const float*)d_in[6];
    const float* Wh   = (const float*)d_in[7];
    const float* bh   = (const float*)d_in[8];
    const float* Wout = (const float*)d_in[9];
    const float* bout = (const float*)d_in[10];
    const float* lam1 = (const float*)d_in[11];
    const float* lam2 = (const float*)d_in[12];

    float* out = (float*)d_out;
    float* ws  = (float*)d_ws;

    hipMemsetAsync(out + 3 * BN, 0, sizeof(float), stream);

    // Fast path: 2 points per thread, 65536 threads, 256 blocks (1/CU)
    pinn_fast3<<<BN / 512, 256, 0, stream>>>(x, y, t, u, v, Win, bin, Wh, bh,
                                             Wout, bout, lam1, lam2, out);
    // General path (runs fully when lambda != 0, else returns at once)
    pinn_jets6<<<dim3(BN / 256, 6), 256, 0, stream>>>(x, y, t, Win, bin, Wh, bh,
                                                      Wout, bout, lam1, lam2, ws);
    pinn_combine<<<BN / 256, 256, 0, stream>>>(ws, u, v, lam1, lam2, out);
}

// Round 10
// 55.703 us; speedup vs baseline: 1.0417x; 1.0417x over previous
//
#include <hip/hip_runtime.h>

typedef float v2f __attribute__((ext_vector_type(2)));

constexpr int BN   = 131072;   // points
constexpr int HID  = 20;       // hidden width
constexpr int NLAY = 7;        // hidden->hidden layers

// LDS layout (floats)
constexpr int OFF_WH   = 0;      // 7*20*20 = 2800
constexpr int OFF_BH   = 2800;   // 7*20    = 140
constexpr int OFF_WIN  = 2940;   // 3*20    = 60
constexpr int OFF_BIN  = 3000;   // 20
constexpr int OFF_WOUT = 3020;   // 20*2    = 40
constexpr int OFF_BOUT = 3060;   // 2
constexpr int LDS_TOT  = 3064;

// ws slots (slow path only)
enum { S_PX = 0, S_PXX, S_PXXX, S_P, S_GPX,
       S_PY, S_PYY, S_PYYY, S_GPY,
       S_D2P, S_D3P, S_D3M, S_XT, S_YT, NSLOT };

__device__ __forceinline__ float fast_tanh(float a) {
    float e = __builtin_amdgcn_exp2f(a * 2.8853900817779268f);
    float r = __builtin_amdgcn_rcpf(e + 1.0f);
    return __builtin_fmaf(-2.0f, r, 1.0f);
}
__device__ __forceinline__ v2f tanh2(v2f a) {
    v2f r; r.x = fast_tanh(a.x); r.y = fast_tanh(a.y); return r;
}
__device__ __forceinline__ v2f splat(float s) { v2f r = {s, s}; return r; }
#define FMA2(a, b, c) __builtin_elementwise_fma((a), (b), (c))

// acc(2 outs) += S.lo * w(2 outs)
__device__ __forceinline__ void pk_fma_lo(v2f& acc, const v2f s, const v2f w) {
    asm("v_pk_fma_f32 %0, %1, %2, %0 op_sel:[0,0,0] op_sel_hi:[0,1,1]"
        : "+v"(acc) : "v"(s), "v"(w));
}
// acc(2 outs) += S.hi * w(2 outs)
__device__ __forceinline__ void pk_fma_hi(v2f& acc, const v2f s, const v2f w) {
    asm("v_pk_fma_f32 %0, %1, %2, %0 op_sel:[1,0,0] op_sel_hi:[1,1,1]"
        : "+v"(acc) : "v"(s), "v"(w));
}

__device__ __forceinline__ void stage_weights(
    float* smem, const float* Win, const float* bin, const float* Wh,
    const float* bh, const float* Wout, const float* bout)
{
    const int tid = threadIdx.x;
    for (int i = tid; i < 2800; i += 256) smem[OFF_WH + i] = Wh[i];
    for (int i = tid; i < 140;  i += 256) smem[OFF_BH + i] = bh[i];
    if (tid < 60) smem[OFF_WIN  + tid] = Win[tid];
    if (tid < 20) smem[OFF_BIN  + tid] = bin[tid];
    if (tid < 40) smem[OFF_WOUT + tid] = Wout[tid];
    if (tid < 2)  smem[OFF_BOUT + tid] = bout[tid];
    __syncthreads();
}

// Two-channel matvec sweep (LDS weights): A1 = W^T S1 (+bias), A2 = W^T S2.
// States/accs neuron-pair packed: 10 x v2f = 20 neurons, one point/thread.
template<bool BIASED>
__device__ __forceinline__ void sweep2(const v2f (&S1)[10], const v2f (&S2)[10],
                                       v2f (&A1)[10], v2f (&A2)[10],
                                       const float* __restrict__ Wl,
                                       const float* __restrict__ bl)
{
    #pragma unroll
    for (int j = 0; j < 10; ++j) {
        if (BIASED) { A1[j].x = bl[2*j]; A1[j].y = bl[2*j+1]; }
        else        A1[j] = splat(0.f);
        A2[j] = splat(0.f);
    }
    #pragma unroll
    for (int i = 0; i < 10; ++i) {
        const float* r0 = &Wl[(2 * i) * HID];
        const float* r1 = &Wl[(2 * i + 1) * HID];
        #pragma unroll
        for (int ob = 0; ob < 5; ++ob) {
            float4 w0 = *(const float4*)&r0[4 * ob];
            float4 w1 = *(const float4*)&r1[4 * ob];
            v2f w0a = {w0.x, w0.y}, w0b = {w0.z, w0.w};
            v2f w1a = {w1.x, w1.y}, w1b = {w1.z, w1.w};
            pk_fma_lo(A1[2*ob],   S1[i], w0a);
            pk_fma_lo(A1[2*ob+1], S1[i], w0b);
            pk_fma_hi(A1[2*ob],   S1[i], w1a);
            pk_fma_hi(A1[2*ob+1], S1[i], w1b);
            pk_fma_lo(A2[2*ob],   S2[i], w0a);
            pk_fma_lo(A2[2*ob+1], S2[i], w0b);
            pk_fma_hi(A2[2*ob],   S2[i], w1a);
            pk_fma_hi(A2[2*ob+1], S2[i], w1b);
        }
    }
}

// ---------------------------------------------------------------- FAST PATH
// lambda1 == lambda2 == 0.  Channel-split across blockIdx.y:
//   slice 0: {V, DX} -> p, psi_x, p_x ; loss part dv^2 + p_x^2
//   slice 1: {V, DY} -> psi_y, p_y    ; loss part du^2 + p_y^2
// 2 channels/wave -> ~80 state+acc regs, 4 waves/SIMD, zero cross-lane ops.
__global__ __launch_bounds__(256, 4) void pinn_fast4(
    const float* __restrict__ x, const float* __restrict__ y, const float* __restrict__ t,
    const float* __restrict__ u, const float* __restrict__ v,
    const float* __restrict__ Win, const float* __restrict__ bin,
    const float* __restrict__ Wh,  const float* __restrict__ bh,
    const float* __restrict__ Wout,const float* __restrict__ bout,
    const float* __restrict__ lam1p, const float* __restrict__ lam2p,
    float* __restrict__ out)
{
    if (lam1p[0] != 0.0f || lam2p[0] != 0.0f) return;   // slow path covers

    __shared__ __align__(16) float smem[LDS_TOT];
    __shared__ float wsum[4];
    stage_weights(smem, Win, bin, Wh, bh, Wout, bout);

    const int tid   = threadIdx.x;
    const int slice = blockIdx.y;            // 0: d/dx, 1: d/dy
    const int pt    = blockIdx.x * 256 + tid;

    const float xv = x[pt], yv = y[pt], tv = t[pt];
    const v2f xv2 = splat(xv), yv2 = splat(yv), tv2 = splat(tv);

    v2f V[10], D[10];

    // ---- input layer
    #pragma unroll
    for (int j = 0; j < 10; ++j) {
        v2f w0 = *(const v2f*)&smem[OFF_WIN + 2*j];
        v2f w1 = *(const v2f*)&smem[OFF_WIN + HID + 2*j];
        v2f w2 = *(const v2f*)&smem[OFF_WIN + 2*HID + 2*j];
        v2f av = *(const v2f*)&smem[OFF_BIN + 2*j];
        av = FMA2(xv2, w0, av);
        av = FMA2(yv2, w1, av);
        av = FMA2(tv2, w2, av);
        v2f s  = tanh2(av);
        v2f s1 = 1.0f - s * s;
        V[j] = s;
        D[j] = s1 * (slice ? w1 : w0);
    }

    // ---- hidden layers
    #pragma unroll 1
    for (int l = 0; l < NLAY; ++l) {
        const float* Wl = &smem[OFF_WH + l * (HID * HID)];
        const float* bl = &smem[OFF_BH + l * HID];
        v2f aV[10], aD[10];
        sweep2<true>(V, D, aV, aD, Wl, bl);
        #pragma unroll
        for (int j = 0; j < 10; ++j) {
            v2f s  = tanh2(aV[j]);
            v2f s1 = 1.0f - s * s;
            V[j] = s;
            D[j] = s1 * aD[j];
        }
    }

    // ---- output layer: col0 -> psi derivative, col1 -> p / p-derivative
    v2f dD = splat(0.f), dP = splat(0.f), dPD = splat(0.f);
    #pragma unroll
    for (int j = 0; j < 10; ++j) {
        v2f w0j = {smem[OFF_WOUT + 4*j],     smem[OFF_WOUT + 4*j + 2]};
        v2f w1j = {smem[OFF_WOUT + 4*j + 1], smem[OFF_WOUT + 4*j + 3]};
        dD  = FMA2(D[j], w0j, dD);
        dP  = FMA2(V[j], w1j, dP);
        dPD = FMA2(D[j], w1j, dPD);
    }
    const float psi_d = dD.x + dD.y;      // psi_x (slice 0) or psi_y (slice 1)
    const float p_d   = dPD.x + dPD.y;    // p_x (slice 0) or p_y (slice 1)

    float term;
    if (slice == 0) {
        const float pv = smem[OFF_BOUT + 1] + dP.x + dP.y;
        out[3*pt+0] = pv;
        out[3*pt+2] = -psi_d;                    // v_pred
        const float dv = v[pt] + psi_d;          // v - v_pred
        term = dv * dv + p_d * p_d;              // dv^2 + p_x^2
    } else {
        out[3*pt+1] = psi_d;                     // u_pred
        const float du = u[pt] - psi_d;          // u - u_pred
        term = du * du + p_d * p_d;              // du^2 + p_y^2
    }

    #pragma unroll
    for (int off = 32; off > 0; off >>= 1) term += __shfl_down(term, off);
    const int lane = tid & 63, wid = tid >> 6;
    if (lane == 0) wsum[wid] = term;
    __syncthreads();
    if (tid == 0) atomicAdd(&out[3*BN], wsum[0] + wsum[1] + wsum[2] + wsum[3]);
}

// ---------------------------------------------------------------- SLOW PATH (lambda != 0)
__global__ __launch_bounds__(256, 3) void pinn_jets6(
    const float* __restrict__ x, const float* __restrict__ y, const float* __restrict__ t,
    const float* __restrict__ Win, const float* __restrict__ bin,
    const float* __restrict__ Wh,  const float* __restrict__ bh,
    const float* __restrict__ Wout,const float* __restrict__ bout,
    const float* __restrict__ lam1p, const float* __restrict__ lam2p,
    float* __restrict__ ws)
{
    if (lam1p[0] == 0.0f && lam2p[0] == 0.0f) return;   // fast path covers

    __shared__ __align__(16) float smem[LDS_TOT];
    stage_weights(smem, Win, bin, Wh, bh, Wout, bout);

    const int pt    = blockIdx.x * 256 + threadIdx.x;
    const int slice = blockIdx.y;

    const float xv = x[pt], yv = y[pt], tv = t[pt];
    const v2f xv2 = splat(xv), yv2 = splat(yv), tv2 = splat(tv);

    if (slice < 4) {
        const float DXT[4] = {1.f, 0.f, 1.f,  1.f};
        const float DYT[4] = {0.f, 1.f, 1.f, -1.f};
        const v2f dxv = splat(DXT[slice]), dyv = splat(DYT[slice]);

        v2f V[10], D1[10], D2[10], D3[10];

        #pragma unroll
        for (int j = 0; j < 10; ++j) {
            v2f w0 = *(const v2f*)&smem[OFF_WIN + 2*j];
            v2f w1 = *(const v2f*)&smem[OFF_WIN + HID + 2*j];
            v2f w2 = *(const v2f*)&smem[OFF_WIN + 2*HID + 2*j];
            v2f av = *(const v2f*)&smem[OFF_BIN + 2*j];
            av = FMA2(xv2, w0, av);
            av = FMA2(yv2, w1, av);
            av = FMA2(tv2, w2, av);
            v2f a1 = dxv * w0;
            a1 = FMA2(dyv, w1, a1);
            v2f s  = tanh2(av);
            v2f s2 = s * s;
            v2f s1 = 1.0f - s2;
            v2f f2 = -2.0f * s * s1;
            v2f f3 = s1 * (4.0f * s2 - 2.0f * s1);
            v2f a1sq = a1 * a1;
            V[j]  = s;
            D1[j] = s1 * a1;
            D2[j] = f2 * a1sq;
            D3[j] = f3 * a1sq * a1;
        }

        #pragma unroll 1
        for (int l = 0; l < NLAY; ++l) {
            const float* Wl = &smem[OFF_WH + l * (HID * HID)];
            const float* bl = &smem[OFF_BH + l * HID];
            v2f aV[10], a1[10];
            sweep2<true >(V,  D1, aV, a1, Wl, bl);
            v2f a2[10], a3[10];
            sweep2<false>(D2, D3, a2, a3, Wl, bl);
            #pragma unroll
            for (int j = 0; j < 10; ++j) {
                v2f s  = tanh2(aV[j]);
                v2f s2 = s * s;
                v2f s1 = 1.0f - s2;
                v2f f2 = -2.0f * s * s1;
                v2f f3 = s1 * (4.0f * s2 - 2.0f * s1);
                v2f u1 = a1[j];
                v2f u1sq = u1 * u1;
                V[j]  = s;
                D1[j] = s1 * u1;
                D2[j] = s1 * a2[j] + f2 * u1sq;
                D3[j] = s1 * a3[j] + 3.0f * f2 * (u1 * a2[j]) + f3 * u1sq * u1;
            }
        }

        v2f d1 = splat(0.f), d2 = splat(0.f), d3 = splat(0.f),
            dP = splat(0.f), dP1 = splat(0.f);
        #pragma unroll
        for (int j = 0; j < 10; ++j) {
            v2f w0j = {smem[OFF_WOUT + 4*j],     smem[OFF_WOUT + 4*j + 2]};
            v2f w1j = {smem[OFF_WOUT + 4*j + 1], smem[OFF_WOUT + 4*j + 3]};
            d1  = FMA2(D1[j], w0j, d1);
            d2  = FMA2(D2[j], w0j, d2);
            d3  = FMA2(D3[j], w0j, d3);
            dP  = FMA2(V[j],  w1j, dP);
            dP1 = FMA2(D1[j], w1j, dP1);
        }
        const float r1 = d1.x + d1.y;
        const float r2 = d2.x + d2.y;
        const float r3 = d3.x + d3.y;

        switch (slice) {
            case 0:
                ws[S_PX  *BN+pt] = r1;
                ws[S_PXX *BN+pt] = r2;
                ws[S_PXXX*BN+pt] = r3;
                ws[S_P   *BN+pt] = smem[OFF_BOUT + 1] + dP.x + dP.y;
                ws[S_GPX *BN+pt] = dP1.x + dP1.y;
                break;
            case 1:
                ws[S_PY  *BN+pt] = r1;
                ws[S_PYY *BN+pt] = r2;
                ws[S_PYYY*BN+pt] = r3;
                ws[S_GPY *BN+pt] = dP1.x + dP1.y;
                break;
            case 2:
                ws[S_D2P *BN+pt] = r2;
                ws[S_D3P *BN+pt] = r3;
                break;
            default:
                ws[S_D3M *BN+pt] = r3;
                break;
        }
    } else {
        v2f V[10], DA[10], DT[10], DAT[10];

        #pragma unroll
        for (int j = 0; j < 10; ++j) {
            v2f w0 = *(const v2f*)&smem[OFF_WIN + 2*j];
            v2f w1 = *(const v2f*)&smem[OFF_WIN + HID + 2*j];
            v2f w2 = *(const v2f*)&smem[OFF_WIN + 2*HID + 2*j];
            v2f av = *(const v2f*)&smem[OFF_BIN + 2*j];
            av = FMA2(xv2, w0, av);
            av = FMA2(yv2, w1, av);
            av = FMA2(tv2, w2, av);
            v2f wa = (slice == 4) ? w0 : w1;
            v2f s  = tanh2(av);
            v2f s1 = 1.0f - s * s;
            v2f f2 = -2.0f * s * s1;
            V[j]   = s;
            DA[j]  = s1 * wa;
            DT[j]  = s1 * w2;
            DAT[j] = f2 * wa * w2;
        }

        #pragma unroll 1
        for (int l = 0; l < NLAY; ++l) {
            const float* Wl = &smem[OFF_WH + l * (HID * HID)];
            const float* bl = &smem[OFF_BH + l * HID];
            v2f aV[10], aA[10];
            sweep2<true >(V,  DA,  aV, aA, Wl, bl);
            v2f aT[10], aAT[10];
            sweep2<false>(DT, DAT, aT, aAT, Wl, bl);
            #pragma unroll
            for (int j = 0; j < 10; ++j) {
                v2f s  = tanh2(aV[j]);
                v2f s1 = 1.0f - s * s;
                v2f f2 = -2.0f * s * s1;
                V[j]   = s;
                DA[j]  = s1 * aA[j];
                DT[j]  = s1 * aT[j];
                DAT[j] = f2 * (aA[j] * aT[j]) + s1 * aAT[j];
            }
        }

        v2f dAT = splat(0.f);
        #pragma unroll
        for (int j = 0; j < 10; ++j) {
            v2f w0j = {smem[OFF_WOUT + 4*j], smem[OFF_WOUT + 4*j + 2]};
            dAT = FMA2(DAT[j], w0j, dAT);
        }
        const float r = dAT.x + dAT.y;
        if (slice == 4) ws[S_XT*BN+pt] = r;
        else            ws[S_YT*BN+pt] = r;
    }
}

__global__ __launch_bounds__(256) void pinn_combine(
    const float* __restrict__ ws,
    const float* __restrict__ u, const float* __restrict__ v,
    const float* __restrict__ lam1p, const float* __restrict__ lam2p,
    float* __restrict__ out)
{
    if (lam1p[0] == 0.0f && lam2p[0] == 0.0f) return;   // fast path covers

    __shared__ float wsum[4];
    const int tid = threadIdx.x;
    const int pt  = blockIdx.x * 256 + tid;

    const float psi_x   = ws[S_PX  *BN+pt];
    const float psi_xx  = ws[S_PXX *BN+pt];
    const float psi_xxx = ws[S_PXXX*BN+pt];
    const float pv      = ws[S_P   *BN+pt];
    const float p_x     = ws[S_GPX *BN+pt];
    const float psi_y   = ws[S_PY  *BN+pt];
    const float psi_yy  = ws[S_PYY *BN+pt];
    const float psi_yyy = ws[S_PYYY*BN+pt];
    const float p_y     = ws[S_GPY *BN+pt];
    const float d2p     = ws[S_D2P *BN+pt];
    const float d3p     = ws[S_D3P *BN+pt];
    const float d3m     = ws[S_D3M *BN+pt];
    const float psi_xt  = ws[S_XT  *BN+pt];
    const float psi_yt  = ws[S_YT  *BN+pt];

    const float psi_xy  = 0.5f * (d2p - psi_xx - psi_yy);
    const float psi_xxy = (d3p - d3m - 2.0f * psi_yyy) * (1.0f / 6.0f);
    const float psi_xyy = (d3p + d3m - 2.0f * psi_xxx) * (1.0f / 6.0f);

    const float u_pred = psi_y;
    const float v_pred = -psi_x;
    const float u_x = psi_xy,  u_y = psi_yy,  u_t = psi_yt;
    const float v_x = -psi_xx, v_y = -psi_xy, v_t = -psi_xt;
    const float u_xx = psi_xxy, u_yy = psi_yyy;
    const float v_xx = -psi_xxx, v_yy = -psi_xyy;

    const float lam1 = lam1p[0];
    const float lam2 = lam2p[0];

    const float f_u = lam1 * (u_t + u_pred * u_x + v_pred * u_y) + p_x - lam2 * (u_xx + u_yy);
    const float f_v = lam1 * (v_t + u_pred * v_x + v_pred * v_y) - lam1 * 9.81f + p_y
                      - lam2 * (v_xx + v_yy);

    out[3*pt+0] = pv;
    out[3*pt+1] = u_pred;
    out[3*pt+2] = v_pred;

    const float du = u[pt] - u_pred;
    const float dv = v[pt] - v_pred;
    float term = du * du + dv * dv + f_u * f_u + f_v * f_v;

    #pragma unroll
    for (int off = 32; off > 0; off >>= 1) term += __shfl_down(term, off);
    const int lane = tid & 63, wid = tid >> 6;
    if (lane == 0) wsum[wid] = term;
    __syncthreads();
    if (tid == 0) atomicAdd(&out[3*BN], wsum[0] + wsum[1] + wsum[2] + wsum[3]);
}

extern "C" void kernel_launch(void* const* d_in, const int* in_sizes, int n_in,
                              void* d_out, int out_size, void* d_ws, size_t ws_size,
                              hipStream_t stream) {
    const float* x    = (const float*)d_in[0];
    const float* y    = (const float*)d_in[1];
    const float* t    = (const float*)d_in[2];
    const float* u    = (const float*)d_in[3];
    const float* v    = (const float*)d_in[4];
    const float* Win  = (const float*)d_in[5];
    const float* bin  = (const float*)d_in[6];
    const float* Wh   = (const float*)d_in[7];
    const float* bh   = (const float*)d_in[8];
    const float* Wout = (const float*)d_in[9];
    const float* bout = (const float*)d_in[10];
    const float* lam1 = (const float*)d_in[11];
    const float* lam2 = (const float*)d_in[12];

    float* out = (float*)d_out;
    float* ws  = (float*)d_ws;

    hipMemsetAsync(out + 3 * BN, 0, sizeof(float), stream);

    // Fast path: channel-split, 2 slices x 512 blocks -> 4096 waves (4/SIMD)
    pinn_fast4<<<dim3(BN / 256, 2), 256, 0, stream>>>(x, y, t, u, v, Win, bin, Wh, bh,
                                                      Wout, bout, lam1, lam2, out);
    // General path (runs fully when lambda != 0, else returns at once)
    pinn_jets6<<<dim3(BN / 256, 6), 256, 0, stream>>>(x, y, t, Win, bin, Wh, bh,
                                                      Wout, bout, lam1, lam2, ws);
    pinn_combine<<<BN / 256, 256, 0, stream>>>(ws, u, v, lam1, lam2, out);
}

// Round 11
// 52.639 us; speedup vs baseline: 1.1023x; 1.0582x over previous
//
#include <hip/hip_runtime.h>

typedef float v2f __attribute__((ext_vector_type(2)));
typedef unsigned long long u64;
typedef unsigned int u32;

constexpr int BN   = 131072;   // points
constexpr int HID  = 20;       // hidden width
constexpr int NLAY = 7;        // hidden->hidden layers

// LDS layout for slow path (floats)
constexpr int OFF_WH   = 0;      // 7*20*20 = 2800
constexpr int OFF_BH   = 2800;   // 7*20    = 140
constexpr int OFF_WIN  = 2940;   // 3*20    = 60
constexpr int OFF_BIN  = 3000;   // 20
constexpr int OFF_WOUT = 3020;   // 20*2    = 40
constexpr int OFF_BOUT = 3060;   // 2
constexpr int LDS_TOT  = 3064;

// ws slots (slow path only)
enum { S_PX = 0, S_PXX, S_PXXX, S_P, S_GPX,
       S_PY, S_PYY, S_PYYY, S_GPY,
       S_D2P, S_D3P, S_D3M, S_XT, S_YT, NSLOT };

__device__ __forceinline__ float fast_tanh(float a) {
    float e = __builtin_amdgcn_exp2f(a * 2.8853900817779268f);
    float r = __builtin_amdgcn_rcpf(e + 1.0f);
    return __builtin_fmaf(-2.0f, r, 1.0f);
}
__device__ __forceinline__ v2f tanh2(v2f a) {
    v2f r; r.x = fast_tanh(a.x); r.y = fast_tanh(a.y); return r;
}
__device__ __forceinline__ v2f splat(float s) { v2f r = {s, s}; return r; }
#define FMA2(a, b, c) __builtin_elementwise_fma((a), (b), (c))

// lane-broadcast: read float from lane `l` (compile-time) into SGPR
__device__ __forceinline__ float rdl(float v, int l) {
    return __int_as_float(__builtin_amdgcn_readlane(__float_as_int(v), l));
}
__device__ __forceinline__ u64 pack2(float lo, float hi) {
    return ((u64)(u32)__float_as_int(hi) << 32) | (u32)__float_as_int(lo);
}

// acc(v2f) += w.lo * st   (weight pair in SGPRs, lo word broadcast)
__device__ __forceinline__ void pk_fma_wlo(v2f& acc, u64 w, v2f st) {
    asm("v_pk_fma_f32 %0, %1, %2, %0 op_sel:[0,0,0] op_sel_hi:[0,1,1]"
        : "+v"(acc) : "s"(w), "v"(st));
}
// acc(v2f) += w.hi * st
__device__ __forceinline__ void pk_fma_whi(v2f& acc, u64 w, v2f st) {
    asm("v_pk_fma_f32 %0, %1, %2, %0 op_sel:[1,0,0] op_sel_hi:[1,1,1]"
        : "+v"(acc) : "s"(w), "v"(st));
}

// ---------------------------------------------------------------- FAST PATH
// lambda1 == lambda2 == 0.  3 channels {V, DX} (v2f-paired) + DY (scalar).
// Weights lane-distributed in VGPR chunks; broadcast via v_readlane -> SGPR
// pairs feeding v_pk_fma / v_fmac.  Only 5 tiny LDS reads per wave-layer.
__global__ __launch_bounds__(256)
__attribute__((amdgpu_waves_per_eu(1, 2)))
void pinn_fast5(
    const float* __restrict__ x, const float* __restrict__ y, const float* __restrict__ t,
    const float* __restrict__ u, const float* __restrict__ v,
    const float* __restrict__ Win, const float* __restrict__ bin,
    const float* __restrict__ Wh,  const float* __restrict__ bh,
    const float* __restrict__ Wout,const float* __restrict__ bout,
    const float* __restrict__ lam1p, const float* __restrict__ lam2p,
    float* __restrict__ out)
{
    if (lam1p[0] != 0.0f || lam2p[0] != 0.0f) return;   // slow path covers

    __shared__ __align__(16) v2f w2s[NLAY * 256];   // weight pairs, lane-major
    __shared__ float bchs[NLAY * 64];               // per-layer bias chunks
    __shared__ float sIn[60], sBin[20], sWout[40], sBout[2];
    __shared__ float wsum[4];

    const int tid = threadIdx.x;

    // stage: pair q of layer l = (Wh[l*400+2q], Wh[l*400+2q+1]) at lane q&63
    for (int idx = tid; idx < NLAY * 256; idx += 256) {
        const int q = idx & 255;
        if (q < 200) {
            const int l = idx >> 8;
            w2s[idx] = *(const v2f*)&Wh[l * 400 + 2 * q];
        }
    }
    for (int idx = tid; idx < NLAY * 64; idx += 256) {
        const int n = idx & 63;
        if (n < 20) bchs[idx] = bh[(idx >> 6) * 20 + n];
    }
    if (tid < 60) sIn[tid]  = Win[tid];
    if (tid < 20) sBin[tid] = bin[tid];
    if (tid < 40) sWout[tid] = Wout[tid];
    if (tid < 2)  sBout[tid] = bout[tid];
    __syncthreads();

    const int lane = tid & 63;
    const int pt   = blockIdx.x * 256 + tid;
    const float xv = x[pt], yv = y[pt], tv = t[pt];

    v2f sVX[20]; float sY[20];

    // ---- input layer
    #pragma unroll
    for (int n = 0; n < 20; ++n) {
        const float w0 = sIn[n], w1 = sIn[20 + n], w2 = sIn[40 + n];
        float a = __builtin_fmaf(tv, w2,
                   __builtin_fmaf(yv, w1,
                    __builtin_fmaf(xv, w0, sBin[n])));
        const float s  = fast_tanh(a);
        const float s1 = 1.0f - s * s;
        v2f t0; t0.x = s; t0.y = s1 * w0;
        sVX[n] = t0;
        sY[n]  = s1 * w1;
    }

    // ---- hidden layers (loop rolled; inner fully unrolled, static indices)
    #pragma unroll 1
    for (int l = 0; l < NLAY; ++l) {
        const v2f* wq = &w2s[l << 8];
        const v2f c0 = wq[lane];
        const v2f c1 = wq[64 + lane];
        const v2f c2 = wq[128 + lane];
        const v2f c3 = wq[192 + lane];
        const float bch = bchs[(l << 6) + lane];

        v2f aVX[20]; float aY[20];
        #pragma unroll
        for (int o = 0; o < 20; ++o) { aVX[o] = splat(0.f); aY[o] = 0.f; }

        #pragma unroll
        for (int i = 0; i < 20; ++i) {
            const v2f svx = sVX[i];
            const float sy = sY[i];
            #pragma unroll
            for (int j = 0; j < 10; ++j) {
                const int q  = i * 10 + j;             // weight pair index
                const v2f c  = (q < 64) ? c0 : (q < 128) ? c1 : (q < 192) ? c2 : c3;
                const int ln = q & 63;
                const float w0 = rdl(c.x, ln);
                const float w1 = rdl(c.y, ln);
                const u64 wp = pack2(w0, w1);
                pk_fma_wlo(aVX[2 * j],     wp, svx);   // {V,DX} += w0*{V,DX}_i
                pk_fma_whi(aVX[2 * j + 1], wp, svx);   // {V,DX} += w1*{V,DX}_i
                aY[2 * j]     = __builtin_fmaf(w0, sy, aY[2 * j]);
                aY[2 * j + 1] = __builtin_fmaf(w1, sy, aY[2 * j + 1]);
            }
        }

        #pragma unroll
        for (int o = 0; o < 20; ++o) {
            const float a  = aVX[o].x + rdl(bch, o);
            const float s  = fast_tanh(a);
            const float s1 = 1.0f - s * s;
            v2f t0; t0.x = s; t0.y = s1 * aVX[o].y;
            sVX[o] = t0;
            sY[o]  = s1 * aY[o];
        }
    }

    // ---- output layer: col0 -> psi, col1 -> p
    float dX = 0.f, dY = 0.f, dP = 0.f, dPX = 0.f, dPY = 0.f;
    #pragma unroll
    for (int n = 0; n < 20; ++n) {
        const float w0 = sWout[2 * n], w1 = sWout[2 * n + 1];
        const float V = sVX[n].x, DX = sVX[n].y, DY = sY[n];
        dX  = __builtin_fmaf(DX, w0, dX);
        dY  = __builtin_fmaf(DY, w0, dY);
        dP  = __builtin_fmaf(V,  w1, dP);
        dPX = __builtin_fmaf(DX, w1, dPX);
        dPY = __builtin_fmaf(DY, w1, dPY);
    }
    const float pv = sBout[1] + dP;

    out[3 * pt + 0] = pv;       // p
    out[3 * pt + 1] = dY;       // u_pred = psi_y
    out[3 * pt + 2] = -dX;      // v_pred = -psi_x

    const float du = u[pt] - dY;
    const float dv = v[pt] + dX;
    // lambda1 = lambda2 = 0 => f_u = p_x, f_v = p_y
    float term = du * du + dv * dv + dPX * dPX + dPY * dPY;

    #pragma unroll
    for (int off = 32; off > 0; off >>= 1) term += __shfl_down(term, off);
    const int wid = tid >> 6;
    if (lane == 0) wsum[wid] = term;
    __syncthreads();
    if (tid == 0) atomicAdd(&out[3 * BN], wsum[0] + wsum[1] + wsum[2] + wsum[3]);
}

// ---------------------------------------------------------------- SLOW PATH (lambda != 0)
__device__ __forceinline__ void pk_fma_lo(v2f& acc, const v2f s, const v2f w) {
    asm("v_pk_fma_f32 %0, %1, %2, %0 op_sel:[0,0,0] op_sel_hi:[0,1,1]"
        : "+v"(acc) : "v"(s), "v"(w));
}
__device__ __forceinline__ void pk_fma_hi(v2f& acc, const v2f s, const v2f w) {
    asm("v_pk_fma_f32 %0, %1, %2, %0 op_sel:[1,0,0] op_sel_hi:[1,1,1]"
        : "+v"(acc) : "v"(s), "v"(w));
}

__device__ __forceinline__ void stage_weights(
    float* smem, const float* Win, const float* bin, const float* Wh,
    const float* bh, const float* Wout, const float* bout)
{
    const int tid = threadIdx.x;
    for (int i = tid; i < 2800; i += 256) smem[OFF_WH + i] = Wh[i];
    for (int i = tid; i < 140;  i += 256) smem[OFF_BH + i] = bh[i];
    if (tid < 60) smem[OFF_WIN  + tid] = Win[tid];
    if (tid < 20) smem[OFF_BIN  + tid] = bin[tid];
    if (tid < 40) smem[OFF_WOUT + tid] = Wout[tid];
    if (tid < 2)  smem[OFF_BOUT + tid] = bout[tid];
    __syncthreads();
}

template<bool BIASED>
__device__ __forceinline__ void sweep2(const v2f (&S1)[10], const v2f (&S2)[10],
                                       v2f (&A1)[10], v2f (&A2)[10],
                                       const float* __restrict__ Wl,
                                       const float* __restrict__ bl)
{
    #pragma unroll
    for (int j = 0; j < 10; ++j) {
        if (BIASED) { A1[j].x = bl[2*j]; A1[j].y = bl[2*j+1]; }
        else        A1[j] = splat(0.f);
        A2[j] = splat(0.f);
    }
    #pragma unroll
    for (int i = 0; i < 10; ++i) {
        const float* r0 = &Wl[(2 * i) * HID];
        const float* r1 = &Wl[(2 * i + 1) * HID];
        #pragma unroll
        for (int ob = 0; ob < 5; ++ob) {
            float4 w0 = *(const float4*)&r0[4 * ob];
            float4 w1 = *(const float4*)&r1[4 * ob];
            v2f w0a = {w0.x, w0.y}, w0b = {w0.z, w0.w};
            v2f w1a = {w1.x, w1.y}, w1b = {w1.z, w1.w};
            pk_fma_lo(A1[2*ob],   S1[i], w0a);
            pk_fma_lo(A1[2*ob+1], S1[i], w0b);
            pk_fma_hi(A1[2*ob],   S1[i], w1a);
            pk_fma_hi(A1[2*ob+1], S1[i], w1b);
            pk_fma_lo(A2[2*ob],   S2[i], w0a);
            pk_fma_lo(A2[2*ob+1], S2[i], w0b);
            pk_fma_hi(A2[2*ob],   S2[i], w1a);
            pk_fma_hi(A2[2*ob+1], S2[i], w1b);
        }
    }
}

__global__ __launch_bounds__(256, 3) void pinn_jets6(
    const float* __restrict__ x, const float* __restrict__ y, const float* __restrict__ t,
    const float* __restrict__ Win, const float* __restrict__ bin,
    const float* __restrict__ Wh,  const float* __restrict__ bh,
    const float* __restrict__ Wout,const float* __restrict__ bout,
    const float* __restrict__ lam1p, const float* __restrict__ lam2p,
    float* __restrict__ ws)
{
    if (lam1p[0] == 0.0f && lam2p[0] == 0.0f) return;   // fast path covers

    __shared__ __align__(16) float smem[LDS_TOT];
    stage_weights(smem, Win, bin, Wh, bh, Wout, bout);

    const int pt    = blockIdx.x * 256 + threadIdx.x;
    const int slice = blockIdx.y;

    const float xv = x[pt], yv = y[pt], tv = t[pt];
    const v2f xv2 = splat(xv), yv2 = splat(yv), tv2 = splat(tv);

    if (slice < 4) {
        const float DXT[4] = {1.f, 0.f, 1.f,  1.f};
        const float DYT[4] = {0.f, 1.f, 1.f, -1.f};
        const v2f dxv = splat(DXT[slice]), dyv = splat(DYT[slice]);

        v2f V[10], D1[10], D2[10], D3[10];

        #pragma unroll
        for (int j = 0; j < 10; ++j) {
            v2f w0 = *(const v2f*)&smem[OFF_WIN + 2*j];
            v2f w1 = *(const v2f*)&smem[OFF_WIN + HID + 2*j];
            v2f w2 = *(const v2f*)&smem[OFF_WIN + 2*HID + 2*j];
            v2f av = *(const v2f*)&smem[OFF_BIN + 2*j];
            av = FMA2(xv2, w0, av);
            av = FMA2(yv2, w1, av);
            av = FMA2(tv2, w2, av);
            v2f a1 = dxv * w0;
            a1 = FMA2(dyv, w1, a1);
            v2f s  = tanh2(av);
            v2f s2 = s * s;
            v2f s1 = 1.0f - s2;
            v2f f2 = -2.0f * s * s1;
            v2f f3 = s1 * (4.0f * s2 - 2.0f * s1);
            v2f a1sq = a1 * a1;
            V[j]  = s;
            D1[j] = s1 * a1;
            D2[j] = f2 * a1sq;
            D3[j] = f3 * a1sq * a1;
        }

        #pragma unroll 1
        for (int l = 0; l < NLAY; ++l) {
            const float* Wl = &smem[OFF_WH + l * (HID * HID)];
            const float* bl = &smem[OFF_BH + l * HID];
            v2f aV[10], a1[10];
            sweep2<true >(V,  D1, aV, a1, Wl, bl);
            v2f a2[10], a3[10];
            sweep2<false>(D2, D3, a2, a3, Wl, bl);
            #pragma unroll
            for (int j = 0; j < 10; ++j) {
                v2f s  = tanh2(aV[j]);
                v2f s2 = s * s;
                v2f s1 = 1.0f - s2;
                v2f f2 = -2.0f * s * s1;
                v2f f3 = s1 * (4.0f * s2 - 2.0f * s1);
                v2f u1 = a1[j];
                v2f u1sq = u1 * u1;
                V[j]  = s;
                D1[j] = s1 * u1;
                D2[j] = s1 * a2[j] + f2 * u1sq;
                D3[j] = s1 * a3[j] + 3.0f * f2 * (u1 * a2[j]) + f3 * u1sq * u1;
            }
        }

        v2f d1 = splat(0.f), d2 = splat(0.f), d3 = splat(0.f),
            dP = splat(0.f), dP1 = splat(0.f);
        #pragma unroll
        for (int j = 0; j < 10; ++j) {
            v2f w0j = {smem[OFF_WOUT + 4*j],     smem[OFF_WOUT + 4*j + 2]};
            v2f w1j = {smem[OFF_WOUT + 4*j + 1], smem[OFF_WOUT + 4*j + 3]};
            d1  = FMA2(D1[j], w0j, d1);
            d2  = FMA2(D2[j], w0j, d2);
            d3  = FMA2(D3[j], w0j, d3);
            dP  = FMA2(V[j],  w1j, dP);
            dP1 = FMA2(D1[j], w1j, dP1);
        }
        const float r1 = d1.x + d1.y;
        const float r2 = d2.x + d2.y;
        const float r3 = d3.x + d3.y;

        switch (slice) {
            case 0:
                ws[S_PX  *BN+pt] = r1;
                ws[S_PXX *BN+pt] = r2;
                ws[S_PXXX*BN+pt] = r3;
                ws[S_P   *BN+pt] = smem[OFF_BOUT + 1] + dP.x + dP.y;
                ws[S_GPX *BN+pt] = dP1.x + dP1.y;
                break;
            case 1:
                ws[S_PY  *BN+pt] = r1;
                ws[S_PYY *BN+pt] = r2;
                ws[S_PYYY*BN+pt] = r3;
                ws[S_GPY *BN+pt] = dP1.x + dP1.y;
                break;
            case 2:
                ws[S_D2P *BN+pt] = r2;
                ws[S_D3P *BN+pt] = r3;
                break;
            default:
                ws[S_D3M *BN+pt] = r3;
                break;
        }
    } else {
        v2f V[10], DA[10], DT[10], DAT[10];

        #pragma unroll
        for (int j = 0; j < 10; ++j) {
            v2f w0 = *(const v2f*)&smem[OFF_WIN + 2*j];
            v2f w1 = *(const v2f*)&smem[OFF_WIN + HID + 2*j];
            v2f w2 = *(const v2f*)&smem[OFF_WIN + 2*HID + 2*j];
            v2f av = *(const v2f*)&smem[OFF_BIN + 2*j];
            av = FMA2(xv2, w0, av);
            av = FMA2(yv2, w1, av);
            av = FMA2(tv2, w2, av);
            v2f wa = (slice == 4) ? w0 : w1;
            v2f s  = tanh2(av);
            v2f s1 = 1.0f - s * s;
            v2f f2 = -2.0f * s * s1;
            V[j]   = s;
            DA[j]  = s1 * wa;
            DT[j]  = s1 * w2;
            DAT[j] = f2 * wa * w2;
        }

        #pragma unroll 1
        for (int l = 0; l < NLAY; ++l) {
            const float* Wl = &smem[OFF_WH + l * (HID * HID)];
            const float* bl = &smem[OFF_BH + l * HID];
            v2f aV[10], aA[10];
            sweep2<true >(V,  DA,  aV, aA, Wl, bl);
            v2f aT[10], aAT[10];
            sweep2<false>(DT, DAT, aT, aAT, Wl, bl);
            #pragma unroll
            for (int j = 0; j < 10; ++j) {
                v2f s  = tanh2(aV[j]);
                v2f s1 = 1.0f - s * s;
                v2f f2 = -2.0f * s * s1;
                V[j]   = s;
                DA[j]  = s1 * aA[j];
                DT[j]  = s1 * aT[j];
                DAT[j] = f2 * (aA[j] * aT[j]) + s1 * aAT[j];
            }
        }

        v2f dAT = splat(0.f);
        #pragma unroll
        for (int j = 0; j < 10; ++j) {
            v2f w0j = {smem[OFF_WOUT + 4*j], smem[OFF_WOUT + 4*j + 2]};
            dAT = FMA2(DAT[j], w0j, dAT);
        }
        const float r = dAT.x + dAT.y;
        if (slice == 4) ws[S_XT*BN+pt] = r;
        else            ws[S_YT*BN+pt] = r;
    }
}

__global__ __launch_bounds__(256) void pinn_combine(
    const float* __restrict__ ws,
    const float* __restrict__ u, const float* __restrict__ v,
    const float* __restrict__ lam1p, const float* __restrict__ lam2p,
    float* __restrict__ out)
{
    if (lam1p[0] == 0.0f && lam2p[0] == 0.0f) return;   // fast path covers

    __shared__ float wsum[4];
    const int tid = threadIdx.x;
    const int pt  = blockIdx.x * 256 + tid;

    const float psi_x   = ws[S_PX  *BN+pt];
    const float psi_xx  = ws[S_PXX *BN+pt];
    const float psi_xxx = ws[S_PXXX*BN+pt];
    const float pv      = ws[S_P   *BN+pt];
    const float p_x     = ws[S_GPX *BN+pt];
    const float psi_y   = ws[S_PY  *BN+pt];
    const float psi_yy  = ws[S_PYY *BN+pt];
    const float psi_yyy = ws[S_PYYY*BN+pt];
    const float p_y     = ws[S_GPY *BN+pt];
    const float d2p     = ws[S_D2P *BN+pt];
    const float d3p     = ws[S_D3P *BN+pt];
    const float d3m     = ws[S_D3M *BN+pt];
    const float psi_xt  = ws[S_XT  *BN+pt];
    const float psi_yt  = ws[S_YT  *BN+pt];

    const float psi_xy  = 0.5f * (d2p - psi_xx - psi_yy);
    const float psi_xxy = (d3p - d3m - 2.0f * psi_yyy) * (1.0f / 6.0f);
    const float psi_xyy = (d3p + d3m - 2.0f * psi_xxx) * (1.0f / 6.0f);

    const float u_pred = psi_y;
    const float v_pred = -psi_x;
    const float u_x = psi_xy,  u_y = psi_yy,  u_t = psi_yt;
    const float v_x = -psi_xx, v_y = -psi_xy, v_t = -psi_xt;
    const float u_xx = psi_xxy, u_yy = psi_yyy;
    const float v_xx = -psi_xxx, v_yy = -psi_xyy;

    const float lam1 = lam1p[0];
    const float lam2 = lam2p[0];

    const float f_u = lam1 * (u_t + u_pred * u_x + v_pred * u_y) + p_x - lam2 * (u_xx + u_yy);
    const float f_v = lam1 * (v_t + u_pred * v_x + v_pred * v_y) - lam1 * 9.81f + p_y
                      - lam2 * (v_xx + v_yy);

    out[3*pt+0] = pv;
    out[3*pt+1] = u_pred;
    out[3*pt+2] = v_pred;

    const float du = u[pt] - u_pred;
    const float dv = v[pt] - v_pred;
    float term = du * du + dv * dv + f_u * f_u + f_v * f_v;

    #pragma unroll
    for (int off = 32; off > 0; off >>= 1) term += __shfl_down(term, off);
    const int lane = tid & 63, wid = tid >> 6;
    if (lane == 0) wsum[wid] = term;
    __syncthreads();
    if (tid == 0) atomicAdd(&out[3*BN], wsum[0] + wsum[1] + wsum[2] + wsum[3]);
}

extern "C" void kernel_launch(void* const* d_in, const int* in_sizes, int n_in,
                              void* d_out, int out_size, void* d_ws, size_t ws_size,
                              hipStream_t stream) {
    const float* x    = (const float*)d_in[0];
    const float* y    = (const float*)d_in[1];
    const float* t    = (const float*)d_in[2];
    const float* u    = (const float*)d_in[3];
    const float* v    = (const float*)d_in[4];
    const float* Win  = (const float*)d_in[5];
    const float* bin  = (const float*)d_in[6];
    const float* Wh   = (const float*)d_in[7];
    const float* bh   = (const float*)d_in[8];
    const float* Wout = (const float*)d_in[9];
    const float* bout = (const float*)d_in[10];
    const float* lam1 = (const float*)d_in[11];
    const float* lam2 = (const float*)d_in[12];

    float* out = (float*)d_out;
    float* ws  = (float*)d_ws;

    hipMemsetAsync(out + 3 * BN, 0, sizeof(float), stream);

    // Fast path: 1 pt/thread, weights broadcast via readlane->SGPR (no LDS wall)
    pinn_fast5<<<BN / 256, 256, 0, stream>>>(x, y, t, u, v, Win, bin, Wh, bh,
                                             Wout, bout, lam1, lam2, out);
    // General path (runs fully when lambda != 0, else returns at once)
    pinn_jets6<<<dim3(BN / 256, 6), 256, 0, stream>>>(x, y, t, Win, bin, Wh, bh,
                                                      Wout, bout, lam1, lam2, ws);
    pinn_combine<<<BN / 256, 256, 0, stream>>>(ws, u, v, lam1, lam2, out);
}

// Round 12
// 48.032 us; speedup vs baseline: 1.2081x; 1.0959x over previous
//
#include <hip/hip_runtime.h>

typedef float v2f __attribute__((ext_vector_type(2)));
typedef unsigned long long u64;
typedef unsigned int u32;

constexpr int BN   = 131072;   // points
constexpr int HID  = 20;       // hidden width
constexpr int NLAY = 7;        // hidden->hidden layers

// LDS layout (floats)
constexpr int OFF_WH   = 0;      // 7*20*20 = 2800
constexpr int OFF_BH   = 2800;   // 7*20    = 140
constexpr int OFF_WIN  = 2940;   // 3*20    = 60
constexpr int OFF_BIN  = 3000;   // 20
constexpr int OFF_WOUT = 3020;   // 20*2    = 40
constexpr int OFF_BOUT = 3060;   // 2
constexpr int LDS_TOT  = 3064;

// ws slots (slow path only)
enum { S_PX = 0, S_PXX, S_PXXX, S_P, S_GPX,
       S_PY, S_PYY, S_PYYY, S_GPY,
       S_D2P, S_D3P, S_D3M, S_XT, S_YT, NSLOT };

__device__ __forceinline__ float fast_tanh(float a) {
    float e = __builtin_amdgcn_exp2f(a * 2.8853900817779268f);
    float r = __builtin_amdgcn_rcpf(e + 1.0f);
    return __builtin_fmaf(-2.0f, r, 1.0f);
}
__device__ __forceinline__ v2f tanh2(v2f a) {
    v2f r; r.x = fast_tanh(a.x); r.y = fast_tanh(a.y); return r;
}
__device__ __forceinline__ v2f splat(float s) { v2f r = {s, s}; return r; }
#define FMA2(a, b, c) __builtin_elementwise_fma((a), (b), (c))

// lane-broadcast: read float from lane l (compile-time) -> SGPR
__device__ __forceinline__ float rdl(float v, int l) {
    return __int_as_float(__builtin_amdgcn_readlane(__float_as_int(v), l));
}
__device__ __forceinline__ u64 pack2(float lo, float hi) {
    return ((u64)(u32)__float_as_int(hi) << 32) | (u32)__float_as_int(lo);
}

// acc(2 outs) += S.lo * w(2 outs)   (weights in VGPR)
__device__ __forceinline__ void pk_fma_lo(v2f& acc, const v2f s, const v2f w) {
    asm("v_pk_fma_f32 %0, %1, %2, %0 op_sel:[0,0,0] op_sel_hi:[0,1,1]"
        : "+v"(acc) : "v"(s), "v"(w));
}
// acc(2 outs) += S.hi * w(2 outs)   (weights in VGPR)
__device__ __forceinline__ void pk_fma_hi(v2f& acc, const v2f s, const v2f w) {
    asm("v_pk_fma_f32 %0, %1, %2, %0 op_sel:[1,0,0] op_sel_hi:[1,1,1]"
        : "+v"(acc) : "v"(s), "v"(w));
}
// acc(2 outs) += S.hi * w(2 outs)   (weight pair in SGPRs)
__device__ __forceinline__ void pk_fma_hi_s(v2f& acc, const v2f s, const u64 w) {
    asm("v_pk_fma_f32 %0, %1, %2, %0 op_sel:[1,0,0] op_sel_hi:[1,1,1]"
        : "+v"(acc) : "v"(s), "s"(w));
}

__device__ __forceinline__ void stage_weights(
    float* smem, const float* Win, const float* bin, const float* Wh,
    const float* bh, const float* Wout, const float* bout)
{
    const int tid = threadIdx.x;
    for (int i = tid; i < 2800; i += 256) smem[OFF_WH + i] = Wh[i];
    for (int i = tid; i < 140;  i += 256) smem[OFF_BH + i] = bh[i];
    if (tid < 60) smem[OFF_WIN  + tid] = Win[tid];
    if (tid < 20) smem[OFF_BIN  + tid] = bin[tid];
    if (tid < 40) smem[OFF_WOUT + tid] = Wout[tid];
    if (tid < 2)  smem[OFF_BOUT + tid] = bout[tid];
    __syncthreads();
}

// ---------------------------------------------------------------- FAST PATH
// lambda1 == lambda2 == 0.  3-channel jet {V, DX, DY}, 1 pt/thread.
// HYBRID weight delivery: even rows via LDS ds_read_b128 (50/layer),
// odd rows + biases lane-resident, broadcast via readlane -> SGPR pair.
// Splits the broadcast traffic across the LDS pipe and the VALU pipe.
__global__ __launch_bounds__(256, 2) void pinn_fast6(
    const float* __restrict__ x, const float* __restrict__ y, const float* __restrict__ t,
    const float* __restrict__ u, const float* __restrict__ v,
    const float* __restrict__ Win, const float* __restrict__ bin,
    const float* __restrict__ Wh,  const float* __restrict__ bh,
    const float* __restrict__ Wout,const float* __restrict__ bout,
    const float* __restrict__ lam1p, const float* __restrict__ lam2p,
    float* __restrict__ out)
{
    if (lam1p[0] != 0.0f || lam2p[0] != 0.0f) return;   // slow path covers

    __shared__ __align__(16) float smem[LDS_TOT];
    __shared__ __align__(8)  v2f  opair[NLAY * 128];  // odd-row pairs (q<100) + bias pairs (100..109)
    __shared__ float wsum[4];

    const int tid  = threadIdx.x;
    const int lane = tid & 63;
    const int pt   = blockIdx.x * 256 + tid;

    // load point data early (overlaps the staging barrier)
    const float xv = x[pt], yv = y[pt], tv = t[pt];
    const float uv = u[pt], vv = v[pt];

    // ---- stage weights
    for (int i = tid; i < 2800; i += 256) smem[OFF_WH + i] = Wh[i];
    if (tid < 60) smem[OFF_WIN  + tid] = Win[tid];
    if (tid < 20) smem[OFF_BIN  + tid] = bin[tid];
    if (tid < 40) smem[OFF_WOUT + tid] = Wout[tid];
    if (tid < 2)  smem[OFF_BOUT + tid] = bout[tid];
    for (int idx = tid; idx < NLAY * 128; idx += 256) {
        const int l = idx >> 7, q = idx & 127;
        if (q < 100) {
            const int i = q / 10, j = q % 10;
            opair[idx] = *(const v2f*)&Wh[l * 400 + (2 * i + 1) * 20 + 2 * j];
        } else if (q < 110) {
            const int j = q - 100;
            v2f b; b.x = bh[l * 20 + 2 * j]; b.y = bh[l * 20 + 2 * j + 1];
            opair[idx] = b;
        }
    }
    __syncthreads();

    v2f V[10], DX[10], DY[10];

    // ---- input layer (neuron-pair packed, as R7)
    const v2f xv2 = splat(xv), yv2 = splat(yv), tv2 = splat(tv);
    #pragma unroll
    for (int j = 0; j < 10; ++j) {
        v2f w0 = *(const v2f*)&smem[OFF_WIN + 2*j];
        v2f w1 = *(const v2f*)&smem[OFF_WIN + HID + 2*j];
        v2f w2 = *(const v2f*)&smem[OFF_WIN + 2*HID + 2*j];
        v2f av = *(const v2f*)&smem[OFF_BIN + 2*j];
        av = FMA2(xv2, w0, av);
        av = FMA2(yv2, w1, av);
        av = FMA2(tv2, w2, av);
        v2f s  = tanh2(av);
        v2f s1 = 1.0f - s * s;
        V[j]  = s;
        DX[j] = s1 * w0;
        DY[j] = s1 * w1;
    }

    // ---- hidden layers
    #pragma unroll 1
    for (int l = 0; l < NLAY; ++l) {
        const float* Wl = &smem[OFF_WH + l * 400];
        const v2f rc0 = opair[(l << 7) + lane];        // odd pairs q = lane
        const v2f rc1 = opair[(l << 7) + 64 + lane];   // odd pairs q = 64+lane (+biases)

        v2f aV[10], aX[10], aY[10];
        #pragma unroll
        for (int j = 0; j < 10; ++j) {                 // bias via readlane (lanes 36..45 of rc1)
            v2f b; b.x = rdl(rc1.x, 36 + j); b.y = rdl(rc1.y, 36 + j);
            aV[j] = b;
            aX[j] = splat(0.f);
            aY[j] = splat(0.f);
        }

        #pragma unroll
        for (int i = 0; i < 10; ++i) {                 // input-neuron pair (2i, 2i+1)
            const float* r0 = &Wl[(2 * i) * HID];      // even row from LDS
            #pragma unroll
            for (int ob = 0; ob < 5; ++ob) {
                float4 w0 = *(const float4*)&r0[4 * ob];
                v2f w0a = {w0.x, w0.y}, w0b = {w0.z, w0.w};
                pk_fma_lo(aV[2*ob],   V[i],  w0a);
                pk_fma_lo(aV[2*ob+1], V[i],  w0b);
                pk_fma_lo(aX[2*ob],   DX[i], w0a);
                pk_fma_lo(aX[2*ob+1], DX[i], w0b);
                pk_fma_lo(aY[2*ob],   DY[i], w0a);
                pk_fma_lo(aY[2*ob+1], DY[i], w0b);
                // odd row via readlane -> SGPR pair (compile-time lane idx)
                const int q0 = i * 10 + 2 * ob, q1 = q0 + 1;
                const v2f cA = (q0 < 64) ? rc0 : rc1;
                const v2f cB = (q1 < 64) ? rc0 : rc1;
                const u64 wp0 = pack2(rdl(cA.x, q0 & 63), rdl(cA.y, q0 & 63));
                const u64 wp1 = pack2(rdl(cB.x, q1 & 63), rdl(cB.y, q1 & 63));
                pk_fma_hi_s(aV[2*ob],   V[i],  wp0);
                pk_fma_hi_s(aV[2*ob+1], V[i],  wp1);
                pk_fma_hi_s(aX[2*ob],   DX[i], wp0);
                pk_fma_hi_s(aX[2*ob+1], DX[i], wp1);
                pk_fma_hi_s(aY[2*ob],   DY[i], wp0);
                pk_fma_hi_s(aY[2*ob+1], DY[i], wp1);
            }
        }

        #pragma unroll
        for (int j = 0; j < 10; ++j) {
            v2f s  = tanh2(aV[j]);
            v2f s1 = 1.0f - s * s;
            V[j]  = s;
            DX[j] = s1 * aX[j];
            DY[j] = s1 * aY[j];
        }
    }

    // ---- output layer: col0 -> psi, col1 -> p
    v2f dX = splat(0.f), dY = splat(0.f), dP = splat(0.f),
        dPX = splat(0.f), dPY = splat(0.f);
    #pragma unroll
    for (int j = 0; j < 10; ++j) {
        v2f w0j = {smem[OFF_WOUT + 4*j],     smem[OFF_WOUT + 4*j + 2]};
        v2f w1j = {smem[OFF_WOUT + 4*j + 1], smem[OFF_WOUT + 4*j + 3]};
        dX  = FMA2(DX[j], w0j, dX);
        dY  = FMA2(DY[j], w0j, dY);
        dP  = FMA2(V[j],  w1j, dP);
        dPX = FMA2(DX[j], w1j, dPX);
        dPY = FMA2(DY[j], w1j, dPY);
    }
    const float psi_x = dX.x + dX.y;
    const float psi_y = dY.x + dY.y;
    const float pv    = smem[OFF_BOUT + 1] + dP.x + dP.y;
    const float p_x   = dPX.x + dPX.y;
    const float p_y   = dPY.x + dPY.y;

    out[3*pt+0] = pv;
    out[3*pt+1] = psi_y;      // u_pred
    out[3*pt+2] = -psi_x;     // v_pred

    const float du = uv - psi_y;
    const float dv = vv + psi_x;
    // lambda1 = lambda2 = 0 => f_u = p_x, f_v = p_y
    float term = du * du + dv * dv + p_x * p_x + p_y * p_y;

    #pragma unroll
    for (int off = 32; off > 0; off >>= 1) term += __shfl_down(term, off);
    const int wid = tid >> 6;
    if (lane == 0) wsum[wid] = term;
    __syncthreads();
    if (tid == 0) atomicAdd(&out[3*BN], wsum[0] + wsum[1] + wsum[2] + wsum[3]);
}

// ---------------------------------------------------------------- SLOW PATH (lambda != 0)
template<bool BIASED>
__device__ __forceinline__ void sweep2(const v2f (&S1)[10], const v2f (&S2)[10],
                                       v2f (&A1)[10], v2f (&A2)[10],
                                       const float* __restrict__ Wl,
                                       const float* __restrict__ bl)
{
    #pragma unroll
    for (int j = 0; j < 10; ++j) {
        if (BIASED) { A1[j].x = bl[2*j]; A1[j].y = bl[2*j+1]; }
        else        A1[j] = splat(0.f);
        A2[j] = splat(0.f);
    }
    #pragma unroll
    for (int i = 0; i < 10; ++i) {
        const float* r0 = &Wl[(2 * i) * HID];
        const float* r1 = &Wl[(2 * i + 1) * HID];
        #pragma unroll
        for (int ob = 0; ob < 5; ++ob) {
            float4 w0 = *(const float4*)&r0[4 * ob];
            float4 w1 = *(const float4*)&r1[4 * ob];
            v2f w0a = {w0.x, w0.y}, w0b = {w0.z, w0.w};
            v2f w1a = {w1.x, w1.y}, w1b = {w1.z, w1.w};
            pk_fma_lo(A1[2*ob],   S1[i], w0a);
            pk_fma_lo(A1[2*ob+1], S1[i], w0b);
            pk_fma_hi(A1[2*ob],   S1[i], w1a);
            pk_fma_hi(A1[2*ob+1], S1[i], w1b);
            pk_fma_lo(A2[2*ob],   S2[i], w0a);
            pk_fma_lo(A2[2*ob+1], S2[i], w0b);
            pk_fma_hi(A2[2*ob],   S2[i], w1a);
            pk_fma_hi(A2[2*ob+1], S2[i], w1b);
        }
    }
}

__global__ __launch_bounds__(256, 3) void pinn_jets6(
    const float* __restrict__ x, const float* __restrict__ y, const float* __restrict__ t,
    const float* __restrict__ Win, const float* __restrict__ bin,
    const float* __restrict__ Wh,  const float* __restrict__ bh,
    const float* __restrict__ Wout,const float* __restrict__ bout,
    const float* __restrict__ lam1p, const float* __restrict__ lam2p,
    float* __restrict__ ws)
{
    if (lam1p[0] == 0.0f && lam2p[0] == 0.0f) return;   // fast path covers

    __shared__ __align__(16) float smem[LDS_TOT];
    stage_weights(smem, Win, bin, Wh, bh, Wout, bout);

    const int pt    = blockIdx.x * 256 + threadIdx.x;
    const int slice = blockIdx.y;

    const float xv = x[pt], yv = y[pt], tv = t[pt];
    const v2f xv2 = splat(xv), yv2 = splat(yv), tv2 = splat(tv);

    if (slice < 4) {
        const float DXT[4] = {1.f, 0.f, 1.f,  1.f};
        const float DYT[4] = {0.f, 1.f, 1.f, -1.f};
        const v2f dxv = splat(DXT[slice]), dyv = splat(DYT[slice]);

        v2f V[10], D1[10], D2[10], D3[10];

        #pragma unroll
        for (int j = 0; j < 10; ++j) {
            v2f w0 = *(const v2f*)&smem[OFF_WIN + 2*j];
            v2f w1 = *(const v2f*)&smem[OFF_WIN + HID + 2*j];
            v2f w2 = *(const v2f*)&smem[OFF_WIN + 2*HID + 2*j];
            v2f av = *(const v2f*)&smem[OFF_BIN + 2*j];
            av = FMA2(xv2, w0, av);
            av = FMA2(yv2, w1, av);
            av = FMA2(tv2, w2, av);
            v2f a1 = dxv * w0;
            a1 = FMA2(dyv, w1, a1);
            v2f s  = tanh2(av);
            v2f s2 = s * s;
            v2f s1 = 1.0f - s2;
            v2f f2 = -2.0f * s * s1;
            v2f f3 = s1 * (4.0f * s2 - 2.0f * s1);
            v2f a1sq = a1 * a1;
            V[j]  = s;
            D1[j] = s1 * a1;
            D2[j] = f2 * a1sq;
            D3[j] = f3 * a1sq * a1;
        }

        #pragma unroll 1
        for (int l = 0; l < NLAY; ++l) {
            const float* Wl = &smem[OFF_WH + l * (HID * HID)];
            const float* bl = &smem[OFF_BH + l * HID];
            v2f aV[10], a1[10];
            sweep2<true >(V,  D1, aV, a1, Wl, bl);
            v2f a2[10], a3[10];
            sweep2<false>(D2, D3, a2, a3, Wl, bl);
            #pragma unroll
            for (int j = 0; j < 10; ++j) {
                v2f s  = tanh2(aV[j]);
                v2f s2 = s * s;
                v2f s1 = 1.0f - s2;
                v2f f2 = -2.0f * s * s1;
                v2f f3 = s1 * (4.0f * s2 - 2.0f * s1);
                v2f u1 = a1[j];
                v2f u1sq = u1 * u1;
                V[j]  = s;
                D1[j] = s1 * u1;
                D2[j] = s1 * a2[j] + f2 * u1sq;
                D3[j] = s1 * a3[j] + 3.0f * f2 * (u1 * a2[j]) + f3 * u1sq * u1;
            }
        }

        v2f d1 = splat(0.f), d2 = splat(0.f), d3 = splat(0.f),
            dP = splat(0.f), dP1 = splat(0.f);
        #pragma unroll
        for (int j = 0; j < 10; ++j) {
            v2f w0j = {smem[OFF_WOUT + 4*j],     smem[OFF_WOUT + 4*j + 2]};
            v2f w1j = {smem[OFF_WOUT + 4*j + 1], smem[OFF_WOUT + 4*j + 3]};
            d1  = FMA2(D1[j], w0j, d1);
            d2  = FMA2(D2[j], w0j, d2);
            d3  = FMA2(D3[j], w0j, d3);
            dP  = FMA2(V[j],  w1j, dP);
            dP1 = FMA2(D1[j], w1j, dP1);
        }
        const float r1 = d1.x + d1.y;
        const float r2 = d2.x + d2.y;
        const float r3 = d3.x + d3.y;

        switch (slice) {
            case 0:
                ws[S_PX  *BN+pt] = r1;
                ws[S_PXX *BN+pt] = r2;
                ws[S_PXXX*BN+pt] = r3;
                ws[S_P   *BN+pt] = smem[OFF_BOUT + 1] + dP.x + dP.y;
                ws[S_GPX *BN+pt] = dP1.x + dP1.y;
                break;
            case 1:
                ws[S_PY  *BN+pt] = r1;
                ws[S_PYY *BN+pt] = r2;
                ws[S_PYYY*BN+pt] = r3;
                ws[S_GPY *BN+pt] = dP1.x + dP1.y;
                break;
            case 2:
                ws[S_D2P *BN+pt] = r2;
                ws[S_D3P *BN+pt] = r3;
                break;
            default:
                ws[S_D3M *BN+pt] = r3;
                break;
        }
    } else {
        v2f V[10], DA[10], DT[10], DAT[10];

        #pragma unroll
        for (int j = 0; j < 10; ++j) {
            v2f w0 = *(const v2f*)&smem[OFF_WIN + 2*j];
            v2f w1 = *(const v2f*)&smem[OFF_WIN + HID + 2*j];
            v2f w2 = *(const v2f*)&smem[OFF_WIN + 2*HID + 2*j];
            v2f av = *(const v2f*)&smem[OFF_BIN + 2*j];
            av = FMA2(xv2, w0, av);
            av = FMA2(yv2, w1, av);
            av = FMA2(tv2, w2, av);
            v2f wa = (slice == 4) ? w0 : w1;
            v2f s  = tanh2(av);
            v2f s1 = 1.0f - s * s;
            v2f f2 = -2.0f * s * s1;
            V[j]   = s;
            DA[j]  = s1 * wa;
            DT[j]  = s1 * w2;
            DAT[j] = f2 * wa * w2;
        }

        #pragma unroll 1
        for (int l = 0; l < NLAY; ++l) {
            const float* Wl = &smem[OFF_WH + l * (HID * HID)];
            const float* bl = &smem[OFF_BH + l * HID];
            v2f aV[10], aA[10];
            sweep2<true >(V,  DA,  aV, aA, Wl, bl);
            v2f aT[10], aAT[10];
            sweep2<false>(DT, DAT, aT, aAT, Wl, bl);
            #pragma unroll
            for (int j = 0; j < 10; ++j) {
                v2f s  = tanh2(aV[j]);
                v2f s1 = 1.0f - s * s;
                v2f f2 = -2.0f * s * s1;
                V[j]   = s;
                DA[j]  = s1 * aA[j];
                DT[j]  = s1 * aT[j];
                DAT[j] = f2 * (aA[j] * aT[j]) + s1 * aAT[j];
            }
        }

        v2f dAT = splat(0.f);
        #pragma unroll
        for (int j = 0; j < 10; ++j) {
            v2f w0j = {smem[OFF_WOUT + 4*j], smem[OFF_WOUT + 4*j + 2]};
            dAT = FMA2(DAT[j], w0j, dAT);
        }
        const float r = dAT.x + dAT.y;
        if (slice == 4) ws[S_XT*BN+pt] = r;
        else            ws[S_YT*BN+pt] = r;
    }
}

__global__ __launch_bounds__(256) void pinn_combine(
    const float* __restrict__ ws,
    const float* __restrict__ u, const float* __restrict__ v,
    const float* __restrict__ lam1p, const float* __restrict__ lam2p,
    float* __restrict__ out)
{
    if (lam1p[0] == 0.0f && lam2p[0] == 0.0f) return;   // fast path covers

    __shared__ float wsum[4];
    const int tid = threadIdx.x;
    const int pt  = blockIdx.x * 256 + tid;

    const float psi_x   = ws[S_PX  *BN+pt];
    const float psi_xx  = ws[S_PXX *BN+pt];
    const float psi_xxx = ws[S_PXXX*BN+pt];
    const float pv      = ws[S_P   *BN+pt];
    const float p_x     = ws[S_GPX *BN+pt];
    const float psi_y   = ws[S_PY  *BN+pt];
    const float psi_yy  = ws[S_PYY *BN+pt];
    const float psi_yyy = ws[S_PYYY*BN+pt];
    const float p_y     = ws[S_GPY *BN+pt];
    const float d2p     = ws[S_D2P *BN+pt];
    const float d3p     = ws[S_D3P *BN+pt];
    const float d3m     = ws[S_D3M *BN+pt];
    const float psi_xt  = ws[S_XT  *BN+pt];
    const float psi_yt  = ws[S_YT  *BN+pt];

    const float psi_xy  = 0.5f * (d2p - psi_xx - psi_yy);
    const float psi_xxy = (d3p - d3m - 2.0f * psi_yyy) * (1.0f / 6.0f);
    const float psi_xyy = (d3p + d3m - 2.0f * psi_xxx) * (1.0f / 6.0f);

    const float u_pred = psi_y;
    const float v_pred = -psi_x;
    const float u_x = psi_xy,  u_y = psi_yy,  u_t = psi_yt;
    const float v_x = -psi_xx, v_y = -psi_xy, v_t = -psi_xt;
    const float u_xx = psi_xxy, u_yy = psi_yyy;
    const float v_xx = -psi_xxx, v_yy = -psi_xyy;

    const float lam1 = lam1p[0];
    const float lam2 = lam2p[0];

    const float f_u = lam1 * (u_t + u_pred * u_x + v_pred * u_y) + p_x - lam2 * (u_xx + u_yy);
    const float f_v = lam1 * (v_t + u_pred * v_x + v_pred * v_y) - lam1 * 9.81f + p_y
                      - lam2 * (v_xx + v_yy);

    out[3*pt+0] = pv;
    out[3*pt+1] = u_pred;
    out[3*pt+2] = v_pred;

    const float du = u[pt] - u_pred;
    const float dv = v[pt] - v_pred;
    float term = du * du + dv * dv + f_u * f_u + f_v * f_v;

    #pragma unroll
    for (int off = 32; off > 0; off >>= 1) term += __shfl_down(term, off);
    const int lane = tid & 63, wid = tid >> 6;
    if (lane == 0) wsum[wid] = term;
    __syncthreads();
    if (tid == 0) atomicAdd(&out[3*BN], wsum[0] + wsum[1] + wsum[2] + wsum[3]);
}

extern "C" void kernel_launch(void* const* d_in, const int* in_sizes, int n_in,
                              void* d_out, int out_size, void* d_ws, size_t ws_size,
                              hipStream_t stream) {
    const float* x    = (const float*)d_in[0];
    const float* y    = (const float*)d_in[1];
    const float* t    = (const float*)d_in[2];
    const float* u    = (const float*)d_in[3];
    const float* v    = (const float*)d_in[4];
    const float* Win  = (const float*)d_in[5];
    const float* bin  = (const float*)d_in[6];
    const float* Wh   = (const float*)d_in[7];
    const float* bh   = (const float*)d_in[8];
    const float* Wout = (const float*)d_in[9];
    const float* bout = (const float*)d_in[10];
    const float* lam1 = (const float*)d_in[11];
    const float* lam2 = (const float*)d_in[12];

    float* out = (float*)d_out;
    float* ws  = (float*)d_ws;

    hipMemsetAsync(out + 3 * BN, 0, sizeof(float), stream);

    // Fast path: 1 pt/thread, hybrid LDS + readlane weight broadcast
    pinn_fast6<<<BN / 256, 256, 0, stream>>>(x, y, t, u, v, Win, bin, Wh, bh,
                                             Wout, bout, lam1, lam2, out);
    // General path (runs fully when lambda != 0, else returns at once)
    pinn_jets6<<<dim3(BN / 256, 6), 256, 0, stream>>>(x, y, t, Win, bin, Wh, bh,
                                                      Wout, bout, lam1, lam2, ws);
    pinn_combine<<<BN / 256, 256, 0, stream>>>(ws, u, v, lam1, lam2, out);
}

// Round 13
// 43.097 us; speedup vs baseline: 1.3464x; 1.1145x over previous
//
#include <hip/hip_runtime.h>

typedef float v2f __attribute__((ext_vector_type(2)));

constexpr int BN   = 131072;   // points
constexpr int HID  = 20;       // hidden width
constexpr int NLAY = 7;        // hidden->hidden layers

// LDS layout (floats)
constexpr int OFF_WH   = 0;      // 7*20*20 = 2800
constexpr int OFF_BH   = 2800;   // 7*20    = 140
constexpr int OFF_WIN  = 2940;   // 3*20    = 60
constexpr int OFF_BIN  = 3000;   // 20
constexpr int OFF_WOUT = 3020;   // 20*2    = 40
constexpr int OFF_BOUT = 3060;   // 2
constexpr int LDS_TOT  = 3064;

// ws slots (slow path only)
enum { S_PX = 0, S_PXX, S_PXXX, S_P, S_GPX,
       S_PY, S_PYY, S_PYYY, S_GPY,
       S_D2P, S_D3P, S_D3M, S_XT, S_YT, NSLOT };

__device__ __forceinline__ float fast_tanh(float a) {
    float e = __builtin_amdgcn_exp2f(a * 2.8853900817779268f);
    float r = __builtin_amdgcn_rcpf(e + 1.0f);
    return __builtin_fmaf(-2.0f, r, 1.0f);
}
__device__ __forceinline__ v2f tanh2(v2f a) {
    v2f r; r.x = fast_tanh(a.x); r.y = fast_tanh(a.y); return r;
}
__device__ __forceinline__ v2f splat(float s) { v2f r = {s, s}; return r; }
#define FMA2(a, b, c) __builtin_elementwise_fma((a), (b), (c))

// acc(2 outs) += S.lo * w(2 outs)
__device__ __forceinline__ void pk_fma_lo(v2f& acc, const v2f s, const v2f w) {
    asm("v_pk_fma_f32 %0, %1, %2, %0 op_sel:[0,0,0] op_sel_hi:[0,1,1]"
        : "+v"(acc) : "v"(s), "v"(w));
}
// acc(2 outs) += S.hi * w(2 outs)
__device__ __forceinline__ void pk_fma_hi(v2f& acc, const v2f s, const v2f w) {
    asm("v_pk_fma_f32 %0, %1, %2, %0 op_sel:[1,0,0] op_sel_hi:[1,1,1]"
        : "+v"(acc) : "v"(s), "v"(w));
}

__device__ __forceinline__ void stage_weights(
    float* smem, const float* Win, const float* bin, const float* Wh,
    const float* bh, const float* Wout, const float* bout)
{
    const int tid = threadIdx.x;
    for (int i = tid; i < 2800; i += 256) smem[OFF_WH + i] = Wh[i];
    for (int i = tid; i < 140;  i += 256) smem[OFF_BH + i] = bh[i];
    if (tid < 60) smem[OFF_WIN  + tid] = Win[tid];
    if (tid < 20) smem[OFF_BIN  + tid] = bin[tid];
    if (tid < 40) smem[OFF_WOUT + tid] = Wout[tid];
    if (tid < 2)  smem[OFF_BOUT + tid] = bout[tid];
    __syncthreads();
}

// Two-channel matvec sweep (slow path): A1 = W^T S1 (+bias), A2 = W^T S2.
template<bool BIASED>
__device__ __forceinline__ void sweep2(const v2f (&S1)[10], const v2f (&S2)[10],
                                       v2f (&A1)[10], v2f (&A2)[10],
                                       const float* __restrict__ Wl,
                                       const float* __restrict__ bl)
{
    #pragma unroll
    for (int j = 0; j < 10; ++j) {
        if (BIASED) { A1[j].x = bl[2*j]; A1[j].y = bl[2*j+1]; }
        else        A1[j] = splat(0.f);
        A2[j] = splat(0.f);
    }
    #pragma unroll
    for (int i = 0; i < 10; ++i) {
        const float* r0 = &Wl[(2 * i) * HID];
        const float* r1 = &Wl[(2 * i + 1) * HID];
        #pragma unroll
        for (int ob = 0; ob < 5; ++ob) {
            float4 w0 = *(const float4*)&r0[4 * ob];
            float4 w1 = *(const float4*)&r1[4 * ob];
            v2f w0a = {w0.x, w0.y}, w0b = {w0.z, w0.w};
            v2f w1a = {w1.x, w1.y}, w1b = {w1.z, w1.w};
            pk_fma_lo(A1[2*ob],   S1[i], w0a);
            pk_fma_lo(A1[2*ob+1], S1[i], w0b);
            pk_fma_hi(A1[2*ob],   S1[i], w1a);
            pk_fma_hi(A1[2*ob+1], S1[i], w1b);
            pk_fma_lo(A2[2*ob],   S2[i], w0a);
            pk_fma_lo(A2[2*ob+1], S2[i], w0b);
            pk_fma_hi(A2[2*ob],   S2[i], w1a);
            pk_fma_hi(A2[2*ob+1], S2[i], w1b);
        }
    }
}

// ---------------------------------------------------------------- MERGED KERNEL
// blockIdx.y == 0: fast path (lambda == 0), software-pipelined 3-channel jet.
// blockIdx.y == 1..6: slow-path jet slices (lambda != 0).
__global__ __launch_bounds__(256)
__attribute__((amdgpu_waves_per_eu(2, 2)))
void pinn_main(
    const float* __restrict__ x, const float* __restrict__ y, const float* __restrict__ t,
    const float* __restrict__ u, const float* __restrict__ v,
    const float* __restrict__ Win, const float* __restrict__ bin,
    const float* __restrict__ Wh,  const float* __restrict__ bh,
    const float* __restrict__ Wout,const float* __restrict__ bout,
    const float* __restrict__ lam1p, const float* __restrict__ lam2p,
    float* __restrict__ ws, float* __restrict__ out)
{
    const bool lam0 = (lam1p[0] == 0.0f && lam2p[0] == 0.0f);
    if (blockIdx.y == 0) { if (!lam0) return; }
    else                 { if (lam0)  return; }

    __shared__ __align__(16) float smem[LDS_TOT];
    __shared__ float wsum[4];

    const int tid = threadIdx.x;
    const int pt  = blockIdx.x * 256 + tid;

    // early global loads (overlap the staging barrier)
    const float xv = x[pt], yv = y[pt], tv = t[pt];
    float uv = 0.f, vv = 0.f;
    if (blockIdx.y == 0) { uv = u[pt]; vv = v[pt]; }

    stage_weights(smem, Win, bin, Wh, bh, Wout, bout);

    const v2f xv2 = splat(xv), yv2 = splat(yv), tv2 = splat(tv);

    if (blockIdx.y == 0) {
        // ======================= FAST PATH =======================
        v2f V[10], DX[10], DY[10];

        #pragma unroll
        for (int j = 0; j < 10; ++j) {
            v2f w0 = *(const v2f*)&smem[OFF_WIN + 2*j];
            v2f w1 = *(const v2f*)&smem[OFF_WIN + HID + 2*j];
            v2f w2 = *(const v2f*)&smem[OFF_WIN + 2*HID + 2*j];
            v2f av = *(const v2f*)&smem[OFF_BIN + 2*j];
            av = FMA2(xv2, w0, av);
            av = FMA2(yv2, w1, av);
            av = FMA2(tv2, w2, av);
            v2f s  = tanh2(av);
            v2f s1 = 1.0f - s * s;
            V[j]  = s;
            DX[j] = s1 * w0;
            DY[j] = s1 * w1;
        }

        #pragma unroll 1
        for (int l = 0; l < NLAY; ++l) {
            const float* Wl = &smem[OFF_WH + l * 400];
            const float* bl = &smem[OFF_BH + l * HID];

            v2f aV[10], aX[10], aY[10];
            #pragma unroll
            for (int j = 0; j < 10; ++j) {
                aV[j].x = bl[2*j]; aV[j].y = bl[2*j+1];
                aX[j] = splat(0.f);
                aY[j] = splat(0.f);
            }

            // software-pipelined weight loads: WE/WO current, NE/NO next
            float4 WE[5], WO[5];
            #pragma unroll
            for (int q = 0; q < 5; ++q) {
                WE[q] = *(const float4*)&Wl[4 * q];          // row 0
                WO[q] = *(const float4*)&Wl[HID + 4 * q];    // row 1
            }

            #pragma unroll
            for (int i = 0; i < 10; ++i) {
                float4 NE[5], NO[5];
                if (i < 9) {
                    #pragma unroll
                    for (int q = 0; q < 5; ++q) {
                        NE[q] = *(const float4*)&Wl[(2 * i + 2) * HID + 4 * q];
                        NO[q] = *(const float4*)&Wl[(2 * i + 3) * HID + 4 * q];
                    }
                }
                #pragma unroll
                for (int ob = 0; ob < 5; ++ob) {
                    v2f w0a = {WE[ob].x, WE[ob].y}, w0b = {WE[ob].z, WE[ob].w};
                    v2f w1a = {WO[ob].x, WO[ob].y}, w1b = {WO[ob].z, WO[ob].w};
                    pk_fma_lo(aV[2*ob],   V[i],  w0a);
                    pk_fma_lo(aV[2*ob+1], V[i],  w0b);
                    pk_fma_hi(aV[2*ob],   V[i],  w1a);
                    pk_fma_hi(aV[2*ob+1], V[i],  w1b);
                    pk_fma_lo(aX[2*ob],   DX[i], w0a);
                    pk_fma_lo(aX[2*ob+1], DX[i], w0b);
                    pk_fma_hi(aX[2*ob],   DX[i], w1a);
                    pk_fma_hi(aX[2*ob+1], DX[i], w1b);
                    pk_fma_lo(aY[2*ob],   DY[i], w0a);
                    pk_fma_lo(aY[2*ob+1], DY[i], w0b);
                    pk_fma_hi(aY[2*ob],   DY[i], w1a);
                    pk_fma_hi(aY[2*ob+1], DY[i], w1b);
                }
                if (i < 9) {
                    #pragma unroll
                    for (int q = 0; q < 5; ++q) { WE[q] = NE[q]; WO[q] = NO[q]; }
                }
            }

            #pragma unroll
            for (int j = 0; j < 10; ++j) {
                v2f s  = tanh2(aV[j]);
                v2f s1 = 1.0f - s * s;
                V[j]  = s;
                DX[j] = s1 * aX[j];
                DY[j] = s1 * aY[j];
            }
        }

        // output layer: col0 -> psi, col1 -> p
        v2f dX = splat(0.f), dY = splat(0.f), dP = splat(0.f),
            dPX = splat(0.f), dPY = splat(0.f);
        #pragma unroll
        for (int j = 0; j < 10; ++j) {
            v2f w0j = {smem[OFF_WOUT + 4*j],     smem[OFF_WOUT + 4*j + 2]};
            v2f w1j = {smem[OFF_WOUT + 4*j + 1], smem[OFF_WOUT + 4*j + 3]};
            dX  = FMA2(DX[j], w0j, dX);
            dY  = FMA2(DY[j], w0j, dY);
            dP  = FMA2(V[j],  w1j, dP);
            dPX = FMA2(DX[j], w1j, dPX);
            dPY = FMA2(DY[j], w1j, dPY);
        }
        const float psi_x = dX.x + dX.y;
        const float psi_y = dY.x + dY.y;
        const float pv    = smem[OFF_BOUT + 1] + dP.x + dP.y;
        const float p_x   = dPX.x + dPX.y;
        const float p_y   = dPY.x + dPY.y;

        out[3*pt+0] = pv;
        out[3*pt+1] = psi_y;      // u_pred
        out[3*pt+2] = -psi_x;     // v_pred

        const float du = uv - psi_y;
        const float dv = vv + psi_x;
        // lambda1 = lambda2 = 0 => f_u = p_x, f_v = p_y
        float term = du * du + dv * dv + p_x * p_x + p_y * p_y;

        #pragma unroll
        for (int off = 32; off > 0; off >>= 1) term += __shfl_down(term, off);
        const int lane = tid & 63, wid = tid >> 6;
        if (lane == 0) wsum[wid] = term;
        __syncthreads();
        if (tid == 0) atomicAdd(&out[3*BN], wsum[0] + wsum[1] + wsum[2] + wsum[3]);
        return;
    }

    // ======================= SLOW PATH (lambda != 0) =======================
    const int slice = blockIdx.y - 1;

    if (slice < 4) {
        const float DXT[4] = {1.f, 0.f, 1.f,  1.f};
        const float DYT[4] = {0.f, 1.f, 1.f, -1.f};
        const v2f dxv = splat(DXT[slice]), dyv = splat(DYT[slice]);

        v2f V[10], D1[10], D2[10], D3[10];

        #pragma unroll
        for (int j = 0; j < 10; ++j) {
            v2f w0 = *(const v2f*)&smem[OFF_WIN + 2*j];
            v2f w1 = *(const v2f*)&smem[OFF_WIN + HID + 2*j];
            v2f w2 = *(const v2f*)&smem[OFF_WIN + 2*HID + 2*j];
            v2f av = *(const v2f*)&smem[OFF_BIN + 2*j];
            av = FMA2(xv2, w0, av);
            av = FMA2(yv2, w1, av);
            av = FMA2(tv2, w2, av);
            v2f a1 = dxv * w0;
            a1 = FMA2(dyv, w1, a1);
            v2f s  = tanh2(av);
            v2f s2 = s * s;
            v2f s1 = 1.0f - s2;
            v2f f2 = -2.0f * s * s1;
            v2f f3 = s1 * (4.0f * s2 - 2.0f * s1);
            v2f a1sq = a1 * a1;
            V[j]  = s;
            D1[j] = s1 * a1;
            D2[j] = f2 * a1sq;
            D3[j] = f3 * a1sq * a1;
        }

        #pragma unroll 1
        for (int l = 0; l < NLAY; ++l) {
            const float* Wl = &smem[OFF_WH + l * (HID * HID)];
            const float* bl = &smem[OFF_BH + l * HID];
            v2f aV[10], a1[10];
            sweep2<true >(V,  D1, aV, a1, Wl, bl);
            v2f a2[10], a3[10];
            sweep2<false>(D2, D3, a2, a3, Wl, bl);
            #pragma unroll
            for (int j = 0; j < 10; ++j) {
                v2f s  = tanh2(aV[j]);
                v2f s2 = s * s;
                v2f s1 = 1.0f - s2;
                v2f f2 = -2.0f * s * s1;
                v2f f3 = s1 * (4.0f * s2 - 2.0f * s1);
                v2f u1 = a1[j];
                v2f u1sq = u1 * u1;
                V[j]  = s;
                D1[j] = s1 * u1;
                D2[j] = s1 * a2[j] + f2 * u1sq;
                D3[j] = s1 * a3[j] + 3.0f * f2 * (u1 * a2[j]) + f3 * u1sq * u1;
            }
        }

        v2f d1 = splat(0.f), d2 = splat(0.f), d3 = splat(0.f),
            dP = splat(0.f), dP1 = splat(0.f);
        #pragma unroll
        for (int j = 0; j < 10; ++j) {
            v2f w0j = {smem[OFF_WOUT + 4*j],     smem[OFF_WOUT + 4*j + 2]};
            v2f w1j = {smem[OFF_WOUT + 4*j + 1], smem[OFF_WOUT + 4*j + 3]};
            d1  = FMA2(D1[j], w0j, d1);
            d2  = FMA2(D2[j], w0j, d2);
            d3  = FMA2(D3[j], w0j, d3);
            dP  = FMA2(V[j],  w1j, dP);
            dP1 = FMA2(D1[j], w1j, dP1);
        }
        const float r1 = d1.x + d1.y;
        const float r2 = d2.x + d2.y;
        const float r3 = d3.x + d3.y;

        switch (slice) {
            case 0:
                ws[S_PX  *BN+pt] = r1;
                ws[S_PXX *BN+pt] = r2;
                ws[S_PXXX*BN+pt] = r3;
                ws[S_P   *BN+pt] = smem[OFF_BOUT + 1] + dP.x + dP.y;
                ws[S_GPX *BN+pt] = dP1.x + dP1.y;
                break;
            case 1:
                ws[S_PY  *BN+pt] = r1;
                ws[S_PYY *BN+pt] = r2;
                ws[S_PYYY*BN+pt] = r3;
                ws[S_GPY *BN+pt] = dP1.x + dP1.y;
                break;
            case 2:
                ws[S_D2P *BN+pt] = r2;
                ws[S_D3P *BN+pt] = r3;
                break;
            default:
                ws[S_D3M *BN+pt] = r3;
                break;
        }
    } else {
        v2f V[10], DA[10], DT[10], DAT[10];

        #pragma unroll
        for (int j = 0; j < 10; ++j) {
            v2f w0 = *(const v2f*)&smem[OFF_WIN + 2*j];
            v2f w1 = *(const v2f*)&smem[OFF_WIN + HID + 2*j];
            v2f w2 = *(const v2f*)&smem[OFF_WIN + 2*HID + 2*j];
            v2f av = *(const v2f*)&smem[OFF_BIN + 2*j];
            av = FMA2(xv2, w0, av);
            av = FMA2(yv2, w1, av);
            av = FMA2(tv2, w2, av);
            v2f wa = (slice == 4) ? w0 : w1;
            v2f s  = tanh2(av);
            v2f s1 = 1.0f - s * s;
            v2f f2 = -2.0f * s * s1;
            V[j]   = s;
            DA[j]  = s1 * wa;
            DT[j]  = s1 * w2;
            DAT[j] = f2 * wa * w2;
        }

        #pragma unroll 1
        for (int l = 0; l < NLAY; ++l) {
            const float* Wl = &smem[OFF_WH + l * (HID * HID)];
            const float* bl = &smem[OFF_BH + l * HID];
            v2f aV[10], aA[10];
            sweep2<true >(V,  DA,  aV, aA, Wl, bl);
            v2f aT[10], aAT[10];
            sweep2<false>(DT, DAT, aT, aAT, Wl, bl);
            #pragma unroll
            for (int j = 0; j < 10; ++j) {
                v2f s  = tanh2(aV[j]);
                v2f s1 = 1.0f - s * s;
                v2f f2 = -2.0f * s * s1;
                V[j]   = s;
                DA[j]  = s1 * aA[j];
                DT[j]  = s1 * aT[j];
                DAT[j] = f2 * (aA[j] * aT[j]) + s1 * aAT[j];
            }
        }

        v2f dAT = splat(0.f);
        #pragma unroll
        for (int j = 0; j < 10; ++j) {
            v2f w0j = {smem[OFF_WOUT + 4*j], smem[OFF_WOUT + 4*j + 2]};
            dAT = FMA2(DAT[j], w0j, dAT);
        }
        const float r = dAT.x + dAT.y;
        if (slice == 4) ws[S_XT*BN+pt] = r;
        else            ws[S_YT*BN+pt] = r;
    }
}

// ---------------------------------------------------------------- SLOW PATH combine
__global__ __launch_bounds__(256) void pinn_combine(
    const float* __restrict__ ws,
    const float* __restrict__ u, const float* __restrict__ v,
    const float* __restrict__ lam1p, const float* __restrict__ lam2p,
    float* __restrict__ out)
{
    if (lam1p[0] == 0.0f && lam2p[0] == 0.0f) return;   // fast path covers

    __shared__ float wsum[4];
    const int tid = threadIdx.x;
    const int pt  = blockIdx.x * 256 + tid;

    const float psi_x   = ws[S_PX  *BN+pt];
    const float psi_xx  = ws[S_PXX *BN+pt];
    const float psi_xxx = ws[S_PXXX*BN+pt];
    const float pv      = ws[S_P   *BN+pt];
    const float p_x     = ws[S_GPX *BN+pt];
    const float psi_y   = ws[S_PY  *BN+pt];
    const float psi_yy  = ws[S_PYY *BN+pt];
    const float psi_yyy = ws[S_PYYY*BN+pt];
    const float p_y     = ws[S_GPY *BN+pt];
    const float d2p     = ws[S_D2P *BN+pt];
    const float d3p     = ws[S_D3P *BN+pt];
    const float d3m     = ws[S_D3M *BN+pt];
    const float psi_xt  = ws[S_XT  *BN+pt];
    const float psi_yt  = ws[S_YT  *BN+pt];

    const float psi_xy  = 0.5f * (d2p - psi_xx - psi_yy);
    const float psi_xxy = (d3p - d3m - 2.0f * psi_yyy) * (1.0f / 6.0f);
    const float psi_xyy = (d3p + d3m - 2.0f * psi_xxx) * (1.0f / 6.0f);

    const float u_pred = psi_y;
    const float v_pred = -psi_x;
    const float u_x = psi_xy,  u_y = psi_yy,  u_t = psi_yt;
    const float v_x = -psi_xx, v_y = -psi_xy, v_t = -psi_xt;
    const float u_xx = psi_xxy, u_yy = psi_yyy;
    const float v_xx = -psi_xxx, v_yy = -psi_xyy;

    const float lam1 = lam1p[0];
    const float lam2 = lam2p[0];

    const float f_u = lam1 * (u_t + u_pred * u_x + v_pred * u_y) + p_x - lam2 * (u_xx + u_yy);
    const float f_v = lam1 * (v_t + u_pred * v_x + v_pred * v_y) - lam1 * 9.81f + p_y
                      - lam2 * (v_xx + v_yy);

    out[3*pt+0] = pv;
    out[3*pt+1] = u_pred;
    out[3*pt+2] = v_pred;

    const float du = u[pt] - u_pred;
    const float dv = v[pt] - v_pred;
    float term = du * du + dv * dv + f_u * f_u + f_v * f_v;

    #pragma unroll
    for (int off = 32; off > 0; off >>= 1) term += __shfl_down(term, off);
    const int lane = tid & 63, wid = tid >> 6;
    if (lane == 0) wsum[wid] = term;
    __syncthreads();
    if (tid == 0) atomicAdd(&out[3*BN], wsum[0] + wsum[1] + wsum[2] + wsum[3]);
}

extern "C" void kernel_launch(void* const* d_in, const int* in_sizes, int n_in,
                              void* d_out, int out_size, void* d_ws, size_t ws_size,
                              hipStream_t stream) {
    const float* x    = (const float*)d_in[0];
    const float* y    = (const float*)d_in[1];
    const float* t    = (const float*)d_in[2];
    const float* u    = (const float*)d_in[3];
    const float* v    = (const float*)d_in[4];
    const float* Win  = (const float*)d_in[5];
    const float* bin  = (const float*)d_in[6];
    const float* Wh   = (const float*)d_in[7];
    const float* bh   = (const float*)d_in[8];
    const float* Wout = (const float*)d_in[9];
    const float* bout = (const float*)d_in[10];
    const float* lam1 = (const float*)d_in[11];
    const float* lam2 = (const float*)d_in[12];

    float* out = (float*)d_out;
    float* ws  = (float*)d_ws;

    hipMemsetAsync(out + 3 * BN, 0, sizeof(float), stream);

    // merged: y=0 fast path (lambda==0), y=1..6 slow-path jet slices (lambda!=0)
    pinn_main<<<dim3(BN / 256, 7), 256, 0, stream>>>(x, y, t, u, v, Win, bin, Wh, bh,
                                                     Wout, bout, lam1, lam2, ws, out);
    pinn_combine<<<BN / 256, 256, 0, stream>>>(ws, u, v, lam1, lam2, out);
}

// Round 14
// 42.969 us; speedup vs baseline: 1.3504x; 1.0030x over previous
//
#include <hip/hip_runtime.h>

typedef float v2f __attribute__((ext_vector_type(2)));

constexpr int BN   = 131072;   // points
constexpr int HID  = 20;       // hidden width
constexpr int NLAY = 7;        // hidden->hidden layers

// LDS layout (floats)
constexpr int OFF_WH   = 0;      // 7*20*20 = 2800
constexpr int OFF_BH   = 2800;   // 7*20    = 140
constexpr int OFF_WIN  = 2940;   // 3*20    = 60
constexpr int OFF_BIN  = 3000;   // 20
constexpr int OFF_WOUT = 3020;   // 20*2    = 40
constexpr int OFF_BOUT = 3060;   // 2
constexpr int LDS_TOT  = 3064;

// ws slots (slow path only)
enum { S_PX = 0, S_PXX, S_PXXX, S_P, S_GPX,
       S_PY, S_PYY, S_PYYY, S_GPY,
       S_D2P, S_D3P, S_D3M, S_XT, S_YT, NSLOT };

__device__ __forceinline__ float fast_tanh(float a) {
    float e = __builtin_amdgcn_exp2f(a * 2.8853900817779268f);
    float r = __builtin_amdgcn_rcpf(e + 1.0f);
    return __builtin_fmaf(-2.0f, r, 1.0f);
}
__device__ __forceinline__ v2f tanh2(v2f a) {
    v2f r; r.x = fast_tanh(a.x); r.y = fast_tanh(a.y); return r;
}
__device__ __forceinline__ v2f splat(float s) { v2f r = {s, s}; return r; }
#define FMA2(a, b, c) __builtin_elementwise_fma((a), (b), (c))

// acc(2 outs) += S.lo * w(2 outs)
__device__ __forceinline__ void pk_fma_lo(v2f& acc, const v2f s, const v2f w) {
    asm("v_pk_fma_f32 %0, %1, %2, %0 op_sel:[0,0,0] op_sel_hi:[0,1,1]"
        : "+v"(acc) : "v"(s), "v"(w));
}
// acc(2 outs) += S.hi * w(2 outs)
__device__ __forceinline__ void pk_fma_hi(v2f& acc, const v2f s, const v2f w) {
    asm("v_pk_fma_f32 %0, %1, %2, %0 op_sel:[1,0,0] op_sel_hi:[1,1,1]"
        : "+v"(acc) : "v"(s), "v"(w));
}

__device__ __forceinline__ void stage_weights(
    float* smem, const float* Win, const float* bin, const float* Wh,
    const float* bh, const float* Wout, const float* bout)
{
    const int tid = threadIdx.x;
    for (int i = tid; i < 2800; i += 256) smem[OFF_WH + i] = Wh[i];
    for (int i = tid; i < 140;  i += 256) smem[OFF_BH + i] = bh[i];
    if (tid < 60) smem[OFF_WIN  + tid] = Win[tid];
    if (tid < 20) smem[OFF_BIN  + tid] = bin[tid];
    if (tid < 40) smem[OFF_WOUT + tid] = Wout[tid];
    if (tid < 2)  smem[OFF_BOUT + tid] = bout[tid];
    __syncthreads();
}

// Two-channel matvec sweep (slow path): A1 = W^T S1 (+bias), A2 = W^T S2.
template<bool BIASED>
__device__ __forceinline__ void sweep2(const v2f (&S1)[10], const v2f (&S2)[10],
                                       v2f (&A1)[10], v2f (&A2)[10],
                                       const float* __restrict__ Wl,
                                       const float* __restrict__ bl)
{
    #pragma unroll
    for (int j = 0; j < 10; ++j) {
        if (BIASED) { A1[j].x = bl[2*j]; A1[j].y = bl[2*j+1]; }
        else        A1[j] = splat(0.f);
        A2[j] = splat(0.f);
    }
    #pragma unroll
    for (int i = 0; i < 10; ++i) {
        const float* r0 = &Wl[(2 * i) * HID];
        const float* r1 = &Wl[(2 * i + 1) * HID];
        #pragma unroll
        for (int ob = 0; ob < 5; ++ob) {
            float4 w0 = *(const float4*)&r0[4 * ob];
            float4 w1 = *(const float4*)&r1[4 * ob];
            v2f w0a = {w0.x, w0.y}, w0b = {w0.z, w0.w};
            v2f w1a = {w1.x, w1.y}, w1b = {w1.z, w1.w};
            pk_fma_lo(A1[2*ob],   S1[i], w0a);
            pk_fma_lo(A1[2*ob+1], S1[i], w0b);
            pk_fma_hi(A1[2*ob],   S1[i], w1a);
            pk_fma_hi(A1[2*ob+1], S1[i], w1b);
            pk_fma_lo(A2[2*ob],   S2[i], w0a);
            pk_fma_lo(A2[2*ob+1], S2[i], w0b);
            pk_fma_hi(A2[2*ob],   S2[i], w1a);
            pk_fma_hi(A2[2*ob+1], S2[i], w1b);
        }
    }
}

// ---------------------------------------------------------------- MERGED KERNEL
// blockIdx.y == 0: fast path (lambda == 0), cross-layer-pipelined 3-channel jet.
// blockIdx.y == 1..6: slow-path jet slices (lambda != 0).
__global__ __launch_bounds__(256)
__attribute__((amdgpu_waves_per_eu(2, 2)))
void pinn_main(
    const float* __restrict__ x, const float* __restrict__ y, const float* __restrict__ t,
    const float* __restrict__ u, const float* __restrict__ v,
    const float* __restrict__ Win, const float* __restrict__ bin,
    const float* __restrict__ Wh,  const float* __restrict__ bh,
    const float* __restrict__ Wout,const float* __restrict__ bout,
    const float* __restrict__ lam1p, const float* __restrict__ lam2p,
    float* __restrict__ ws, float* __restrict__ out)
{
    const bool lam0 = (lam1p[0] == 0.0f && lam2p[0] == 0.0f);
    if (blockIdx.y == 0) { if (!lam0) return; }
    else                 { if (lam0)  return; }

    __shared__ __align__(16) float smem[LDS_TOT];
    __shared__ float wsum[4];

    const int tid = threadIdx.x;
    const int pt  = blockIdx.x * 256 + tid;

    // early global loads (overlap the staging barrier)
    const float xv = x[pt], yv = y[pt], tv = t[pt];
    float uv = 0.f, vv = 0.f;
    if (blockIdx.y == 0) { uv = u[pt]; vv = v[pt]; }

    stage_weights(smem, Win, bin, Wh, bh, Wout, bout);

    const v2f xv2 = splat(xv), yv2 = splat(yv), tv2 = splat(tv);

    if (blockIdx.y == 0) {
        // ======================= FAST PATH =======================
        v2f V[10], DX[10], DY[10];

        #pragma unroll
        for (int j = 0; j < 10; ++j) {
            v2f w0 = *(const v2f*)&smem[OFF_WIN + 2*j];
            v2f w1 = *(const v2f*)&smem[OFF_WIN + HID + 2*j];
            v2f w2 = *(const v2f*)&smem[OFF_WIN + 2*HID + 2*j];
            v2f av = *(const v2f*)&smem[OFF_BIN + 2*j];
            av = FMA2(xv2, w0, av);
            av = FMA2(yv2, w1, av);
            av = FMA2(tv2, w2, av);
            v2f s  = tanh2(av);
            v2f s1 = 1.0f - s * s;
            V[j]  = s;
            DX[j] = s1 * w0;
            DY[j] = s1 * w1;
        }

        // peel: preload layer 0 rows 0,1 (these loads overlap the input layer)
        float4 WE[5], WO[5];
        #pragma unroll
        for (int q = 0; q < 5; ++q) {
            WE[q] = *(const float4*)&smem[OFF_WH + 4 * q];
            WO[q] = *(const float4*)&smem[OFF_WH + HID + 4 * q];
        }

        #pragma unroll 1
        for (int l = 0; l < NLAY; ++l) {
            const float* Wl    = &smem[OFF_WH + l * 400];
            const float* Wnext = &smem[OFF_WH + ((l == NLAY - 1) ? l : l + 1) * 400];
            const float* bl    = &smem[OFF_BH + l * HID];

            v2f aV[10], aX[10], aY[10];
            #pragma unroll
            for (int j = 0; j < 10; ++j) {
                aV[j].x = bl[2*j]; aV[j].y = bl[2*j+1];
                aX[j] = splat(0.f);
                aY[j] = splat(0.f);
            }

            #pragma unroll
            for (int i = 0; i < 10; ++i) {
                // prefetch: i<9 -> this layer's next row pair;
                //           i==9 -> NEXT layer's rows 0,1 (hide under mixing)
                float4 NE[5], NO[5];
                const float* n0 = (i < 9) ? &Wl[(2 * i + 2) * HID] : &Wnext[0];
                const float* n1 = (i < 9) ? &Wl[(2 * i + 3) * HID] : &Wnext[HID];
                #pragma unroll
                for (int q = 0; q < 5; ++q) {
                    NE[q] = *(const float4*)&n0[4 * q];
                    NO[q] = *(const float4*)&n1[4 * q];
                }
                #pragma unroll
                for (int ob = 0; ob < 5; ++ob) {
                    v2f w0a = {WE[ob].x, WE[ob].y}, w0b = {WE[ob].z, WE[ob].w};
                    v2f w1a = {WO[ob].x, WO[ob].y}, w1b = {WO[ob].z, WO[ob].w};
                    pk_fma_lo(aV[2*ob],   V[i],  w0a);
                    pk_fma_lo(aV[2*ob+1], V[i],  w0b);
                    pk_fma_hi(aV[2*ob],   V[i],  w1a);
                    pk_fma_hi(aV[2*ob+1], V[i],  w1b);
                    pk_fma_lo(aX[2*ob],   DX[i], w0a);
                    pk_fma_lo(aX[2*ob+1], DX[i], w0b);
                    pk_fma_hi(aX[2*ob],   DX[i], w1a);
                    pk_fma_hi(aX[2*ob+1], DX[i], w1b);
                    pk_fma_lo(aY[2*ob],   DY[i], w0a);
                    pk_fma_lo(aY[2*ob+1], DY[i], w0b);
                    pk_fma_hi(aY[2*ob],   DY[i], w1a);
                    pk_fma_hi(aY[2*ob+1], DY[i], w1b);
                }
                #pragma unroll
                for (int q = 0; q < 5; ++q) { WE[q] = NE[q]; WO[q] = NO[q]; }
            }

            // mixing phase runs with next layer's rows 0,1 already in flight
            #pragma unroll
            for (int j = 0; j < 10; ++j) {
                v2f s  = tanh2(aV[j]);
                v2f s1 = 1.0f - s * s;
                V[j]  = s;
                DX[j] = s1 * aX[j];
                DY[j] = s1 * aY[j];
            }
        }

        // output layer: col0 -> psi, col1 -> p
        v2f dX = splat(0.f), dY = splat(0.f), dP = splat(0.f),
            dPX = splat(0.f), dPY = splat(0.f);
        #pragma unroll
        for (int j = 0; j < 10; ++j) {
            v2f w0j = {smem[OFF_WOUT + 4*j],     smem[OFF_WOUT + 4*j + 2]};
            v2f w1j = {smem[OFF_WOUT + 4*j + 1], smem[OFF_WOUT + 4*j + 3]};
            dX  = FMA2(DX[j], w0j, dX);
            dY  = FMA2(DY[j], w0j, dY);
            dP  = FMA2(V[j],  w1j, dP);
            dPX = FMA2(DX[j], w1j, dPX);
            dPY = FMA2(DY[j], w1j, dPY);
        }
        const float psi_x = dX.x + dX.y;
        const float psi_y = dY.x + dY.y;
        const float pv    = smem[OFF_BOUT + 1] + dP.x + dP.y;
        const float p_x   = dPX.x + dPX.y;
        const float p_y   = dPY.x + dPY.y;

        out[3*pt+0] = pv;
        out[3*pt+1] = psi_y;      // u_pred
        out[3*pt+2] = -psi_x;     // v_pred

        const float du = uv - psi_y;
        const float dv = vv + psi_x;
        // lambda1 = lambda2 = 0 => f_u = p_x, f_v = p_y
        float term = du * du + dv * dv + p_x * p_x + p_y * p_y;

        #pragma unroll
        for (int off = 32; off > 0; off >>= 1) term += __shfl_down(term, off);
        const int lane = tid & 63, wid = tid >> 6;
        if (lane == 0) wsum[wid] = term;
        __syncthreads();
        if (tid == 0) atomicAdd(&out[3*BN], wsum[0] + wsum[1] + wsum[2] + wsum[3]);
        return;
    }

    // ======================= SLOW PATH (lambda != 0) =======================
    const int slice = blockIdx.y - 1;

    if (slice < 4) {
        const float DXT[4] = {1.f, 0.f, 1.f,  1.f};
        const float DYT[4] = {0.f, 1.f, 1.f, -1.f};
        const v2f dxv = splat(DXT[slice]), dyv = splat(DYT[slice]);

        v2f V[10], D1[10], D2[10], D3[10];

        #pragma unroll
        for (int j = 0; j < 10; ++j) {
            v2f w0 = *(const v2f*)&smem[OFF_WIN + 2*j];
            v2f w1 = *(const v2f*)&smem[OFF_WIN + HID + 2*j];
            v2f w2 = *(const v2f*)&smem[OFF_WIN + 2*HID + 2*j];
            v2f av = *(const v2f*)&smem[OFF_BIN + 2*j];
            av = FMA2(xv2, w0, av);
            av = FMA2(yv2, w1, av);
            av = FMA2(tv2, w2, av);
            v2f a1 = dxv * w0;
            a1 = FMA2(dyv, w1, a1);
            v2f s  = tanh2(av);
            v2f s2 = s * s;
            v2f s1 = 1.0f - s2;
            v2f f2 = -2.0f * s * s1;
            v2f f3 = s1 * (4.0f * s2 - 2.0f * s1);
            v2f a1sq = a1 * a1;
            V[j]  = s;
            D1[j] = s1 * a1;
            D2[j] = f2 * a1sq;
            D3[j] = f3 * a1sq * a1;
        }

        #pragma unroll 1
        for (int l = 0; l < NLAY; ++l) {
            const float* Wl = &smem[OFF_WH + l * (HID * HID)];
            const float* bl = &smem[OFF_BH + l * HID];
            v2f aV[10], a1[10];
            sweep2<true >(V,  D1, aV, a1, Wl, bl);
            v2f a2[10], a3[10];
            sweep2<false>(D2, D3, a2, a3, Wl, bl);
            #pragma unroll
            for (int j = 0; j < 10; ++j) {
                v2f s  = tanh2(aV[j]);
                v2f s2 = s * s;
                v2f s1 = 1.0f - s2;
                v2f f2 = -2.0f * s * s1;
                v2f f3 = s1 * (4.0f * s2 - 2.0f * s1);
                v2f u1 = a1[j];
                v2f u1sq = u1 * u1;
                V[j]  = s;
                D1[j] = s1 * u1;
                D2[j] = s1 * a2[j] + f2 * u1sq;
                D3[j] = s1 * a3[j] + 3.0f * f2 * (u1 * a2[j]) + f3 * u1sq * u1;
            }
        }

        v2f d1 = splat(0.f), d2 = splat(0.f), d3 = splat(0.f),
            dP = splat(0.f), dP1 = splat(0.f);
        #pragma unroll
        for (int j = 0; j < 10; ++j) {
            v2f w0j = {smem[OFF_WOUT + 4*j],     smem[OFF_WOUT + 4*j + 2]};
            v2f w1j = {smem[OFF_WOUT + 4*j + 1], smem[OFF_WOUT + 4*j + 3]};
            d1  = FMA2(D1[j], w0j, d1);
            d2  = FMA2(D2[j], w0j, d2);
            d3  = FMA2(D3[j], w0j, d3);
            dP  = FMA2(V[j],  w1j, dP);
            dP1 = FMA2(D1[j], w1j, dP1);
        }
        const float r1 = d1.x + d1.y;
        const float r2 = d2.x + d2.y;
        const float r3 = d3.x + d3.y;

        switch (slice) {
            case 0:
                ws[S_PX  *BN+pt] = r1;
                ws[S_PXX *BN+pt] = r2;
                ws[S_PXXX*BN+pt] = r3;
                ws[S_P   *BN+pt] = smem[OFF_BOUT + 1] + dP.x + dP.y;
                ws[S_GPX *BN+pt] = dP1.x + dP1.y;
                break;
            case 1:
                ws[S_PY  *BN+pt] = r1;
                ws[S_PYY *BN+pt] = r2;
                ws[S_PYYY*BN+pt] = r3;
                ws[S_GPY *BN+pt] = dP1.x + dP1.y;
                break;
            case 2:
                ws[S_D2P *BN+pt] = r2;
                ws[S_D3P *BN+pt] = r3;
                break;
            default:
                ws[S_D3M *BN+pt] = r3;
                break;
        }
    } else {
        v2f V[10], DA[10], DT[10], DAT[10];

        #pragma unroll
        for (int j = 0; j < 10; ++j) {
            v2f w0 = *(const v2f*)&smem[OFF_WIN + 2*j];
            v2f w1 = *(const v2f*)&smem[OFF_WIN + HID + 2*j];
            v2f w2 = *(const v2f*)&smem[OFF_WIN + 2*HID + 2*j];
            v2f av = *(const v2f*)&smem[OFF_BIN + 2*j];
            av = FMA2(xv2, w0, av);
            av = FMA2(yv2, w1, av);
            av = FMA2(tv2, w2, av);
            v2f wa = (slice == 4) ? w0 : w1;
            v2f s  = tanh2(av);
            v2f s1 = 1.0f - s * s;
            v2f f2 = -2.0f * s * s1;
            V[j]   = s;
            DA[j]  = s1 * wa;
            DT[j]  = s1 * w2;
            DAT[j] = f2 * wa * w2;
        }

        #pragma unroll 1
        for (int l = 0; l < NLAY; ++l) {
            const float* Wl = &smem[OFF_WH + l * (HID * HID)];
            const float* bl = &smem[OFF_BH + l * HID];
            v2f aV[10], aA[10];
            sweep2<true >(V,  DA,  aV, aA, Wl, bl);
            v2f aT[10], aAT[10];
            sweep2<false>(DT, DAT, aT, aAT, Wl, bl);
            #pragma unroll
            for (int j = 0; j < 10; ++j) {
                v2f s  = tanh2(aV[j]);
                v2f s1 = 1.0f - s * s;
                v2f f2 = -2.0f * s * s1;
                V[j]   = s;
                DA[j]  = s1 * aA[j];
                DT[j]  = s1 * aT[j];
                DAT[j] = f2 * (aA[j] * aT[j]) + s1 * aAT[j];
            }
        }

        v2f dAT = splat(0.f);
        #pragma unroll
        for (int j = 0; j < 10; ++j) {
            v2f w0j = {smem[OFF_WOUT + 4*j], smem[OFF_WOUT + 4*j + 2]};
            dAT = FMA2(DAT[j], w0j, dAT);
        }
        const float r = dAT.x + dAT.y;
        if (slice == 4) ws[S_XT*BN+pt] = r;
        else            ws[S_YT*BN+pt] = r;
    }
}

// ---------------------------------------------------------------- SLOW PATH combine
__global__ __launch_bounds__(256) void pinn_combine(
    const float* __restrict__ ws,
    const float* __restrict__ u, const float* __restrict__ v,
    const float* __restrict__ lam1p, const float* __restrict__ lam2p,
    float* __restrict__ out)
{
    if (lam1p[0] == 0.0f && lam2p[0] == 0.0f) return;   // fast path covers

    __shared__ float wsum[4];
    const int tid = threadIdx.x;
    const int pt  = blockIdx.x * 256 + tid;

    const float psi_x   = ws[S_PX  *BN+pt];
    const float psi_xx  = ws[S_PXX *BN+pt];
    const float psi_xxx = ws[S_PXXX*BN+pt];
    const float pv      = ws[S_P   *BN+pt];
    const float p_x     = ws[S_GPX *BN+pt];
    const float psi_y   = ws[S_PY  *BN+pt];
    const float psi_yy  = ws[S_PYY *BN+pt];
    const float psi_yyy = ws[S_PYYY*BN+pt];
    const float p_y     = ws[S_GPY *BN+pt];
    const float d2p     = ws[S_D2P *BN+pt];
    const float d3p     = ws[S_D3P *BN+pt];
    const float d3m     = ws[S_D3M *BN+pt];
    const float psi_xt  = ws[S_XT  *BN+pt];
    const float psi_yt  = ws[S_YT  *BN+pt];

    const float psi_xy  = 0.5f * (d2p - psi_xx - psi_yy);
    const float psi_xxy = (d3p - d3m - 2.0f * psi_yyy) * (1.0f / 6.0f);
    const float psi_xyy = (d3p + d3m - 2.0f * psi_xxx) * (1.0f / 6.0f);

    const float u_pred = psi_y;
    const float v_pred = -psi_x;
    const float u_x = psi_xy,  u_y = psi_yy,  u_t = psi_yt;
    const float v_x = -psi_xx, v_y = -psi_xy, v_t = -psi_xt;
    const float u_xx = psi_xxy, u_yy = psi_yyy;
    const float v_xx = -psi_xxx, v_yy = -psi_xyy;

    const float lam1 = lam1p[0];
    const float lam2 = lam2p[0];

    const float f_u = lam1 * (u_t + u_pred * u_x + v_pred * u_y) + p_x - lam2 * (u_xx + u_yy);
    const float f_v = lam1 * (v_t + u_pred * v_x + v_pred * v_y) - lam1 * 9.81f + p_y
                      - lam2 * (v_xx + v_yy);

    out[3*pt+0] = pv;
    out[3*pt+1] = u_pred;
    out[3*pt+2] = v_pred;

    const float du = u[pt] - u_pred;
    const float dv = v[pt] - v_pred;
    float term = du * du + dv * dv + f_u * f_u + f_v * f_v;

    #pragma unroll
    for (int off = 32; off > 0; off >>= 1) term += __shfl_down(term, off);
    const int lane = tid & 63, wid = tid >> 6;
    if (lane == 0) wsum[wid] = term;
    __syncthreads();
    if (tid == 0) atomicAdd(&out[3*BN], wsum[0] + wsum[1] + wsum[2] + wsum[3]);
}

extern "C" void kernel_launch(void* const* d_in, const int* in_sizes, int n_in,
                              void* d_out, int out_size, void* d_ws, size_t ws_size,
                              hipStream_t stream) {
    const float* x    = (const float*)d_in[0];
    const float* y    = (const float*)d_in[1];
    const float* t    = (const float*)d_in[2];
    const float* u    = (const float*)d_in[3];
    const float* v    = (const float*)d_in[4];
    const float* Win  = (const float*)d_in[5];
    const float* bin  = (const float*)d_in[6];
    const float* Wh   = (const float*)d_in[7];
    const float* bh   = (const float*)d_in[8];
    const float* Wout = (const float*)d_in[9];
    const float* bout = (const float*)d_in[10];
    const float* lam1 = (const float*)d_in[11];
    const float* lam2 = (const float*)d_in[12];

    float* out = (float*)d_out;
    float* ws  = (float*)d_ws;

    hipMemsetAsync(out + 3 * BN, 0, sizeof(float), stream);

    // merged: y=0 fast path (lambda==0), y=1..6 slow-path jet slices (lambda!=0)
    pinn_main<<<dim3(BN / 256, 7), 256, 0, stream>>>(x, y, t, u, v, Win, bin, Wh, bh,
                                                     Wout, bout, lam1, lam2, ws, out);
    pinn_combine<<<BN / 256, 256, 0, stream>>>(ws, u, v, lam1, lam2, out);
}